// Round 1
// 1587.068 us; speedup vs baseline: 1.0427x; 1.0427x over previous
//
#include <hip/hip_runtime.h>
#include <hip/hip_bf16.h>
#include <cmath>

#define B_    2
#define T_    1024
#define BT_   2048
#define C_    1024
#define H_    16
#define NH_   4096
#define E_    2
#define WIN_  256
#define G_    4          // attention hb-chunk size

typedef unsigned short u16;
typedef __attribute__((ext_vector_type(8))) short short8;
typedef __attribute__((ext_vector_type(4))) float f32x4;

__device__ __forceinline__ u16 f2b(float f) {
    __hip_bfloat16 h = __float2bfloat16(f);
    return *(u16*)&h;
}
__device__ __forceinline__ float b2f(u16 u) {
    __hip_bfloat16 h; *(u16*)&h = u;
    return __bfloat162float(h);
}

// ============================================================================
// MFMA GEMM, TN path: A bf16 [M][K] (lda), B bf16 [N][K] (ldb).
// TILE: 128 x (TNJ*32). 4 waves in 2x2. Batched via z with offset coefs.
// EPI: 0=f32, 1=bf16, 2=scores(scale+window-mask,f32), 3=x1(bias+res,f32),
//      4=bf16+bias, 5=f32 res+coef*(v+bias), 6=f32 +=coef*(v+bias)
// ============================================================================
template<int TNJ, int EPI>
__global__ __launch_bounds__(256) void gemm_tn(
    const u16* __restrict__ A, const u16* __restrict__ B,
    float* __restrict__ Cf, u16* __restrict__ Cb,
    const float* __restrict__ bias, const float* __restrict__ res,
    const float* __restrict__ coef,
    int K, int lda, int ldb, int ldc,
    int hb0, long aCz, long aCb, long aCh,
    long bCb, long bCh, long cCz, long cCb, long cCh)
{
    constexpr int TN = TNJ * 32;
    __shared__ u16 As[128][40];
    __shared__ u16 Bs[TN][40];
    int tid = threadIdx.x;
    int z = blockIdx.z;
    int hb = hb0 + z;
    int hh = hb >> 1, bb = hb & 1;
    const u16* Ap = A + aCz * z + aCb * bb + aCh * hh + (size_t)blockIdx.y * 128 * lda;
    const u16* Bp = B + bCb * bb + bCh * hh + (size_t)blockIdx.x * TN * ldb;
    size_t cOff = (size_t)(cCz * z + cCb * bb + cCh * hh);

    f32x4 acc[4][TNJ];
    #pragma unroll
    for (int i = 0; i < 4; ++i)
        #pragma unroll
        for (int j = 0; j < TNJ; ++j)
            acc[i][j] = (f32x4){0.f, 0.f, 0.f, 0.f};

    int lane = tid & 63, w = tid >> 6;
    int wr = (w >> 1) * 64, wc = (w & 1) * (TNJ * 16);
    int fm = lane & 15, fk = (lane >> 4) * 8;

    for (int k0 = 0; k0 < K; k0 += 32) {
        {   // stage A: 128x32
            int r = tid >> 1, hf = (tid & 1) * 16;
            const u16* s = Ap + (size_t)r * lda + k0 + hf;
            *(float4*)&As[r][hf]     = *(const float4*)s;
            *(float4*)&As[r][hf + 8] = *(const float4*)(s + 8);
        }
        if (TN == 128) {  // stage B: 128x32
            int r = tid >> 1, hf = (tid & 1) * 16;
            const u16* s = Bp + (size_t)r * ldb + k0 + hf;
            *(float4*)&Bs[r][hf]     = *(const float4*)s;
            *(float4*)&Bs[r][hf + 8] = *(const float4*)(s + 8);
        } else {          // 64x32
            int r = tid >> 2, hf = (tid & 3) * 8;
            *(float4*)&Bs[r][hf] = *(const float4*)(Bp + (size_t)r * ldb + k0 + hf);
        }
        __syncthreads();
        short8 af[4], bf[TNJ];
        #pragma unroll
        for (int i = 0; i < 4; ++i) af[i] = *(const short8*)&As[wr + i * 16 + fm][fk];
        #pragma unroll
        for (int j = 0; j < TNJ; ++j) bf[j] = *(const short8*)&Bs[wc + j * 16 + fm][fk];
        #pragma unroll
        for (int i = 0; i < 4; ++i)
            #pragma unroll
            for (int j = 0; j < TNJ; ++j)
                acc[i][j] = __builtin_amdgcn_mfma_f32_16x16x32_bf16(af[i], bf[j], acc[i][j], 0, 0, 0);
        __syncthreads();
    }

    int rBase = blockIdx.y * 128 + wr + (lane >> 4) * 4;
    int cBase = blockIdx.x * TN + wc + fm;
    #pragma unroll
    for (int i = 0; i < 4; ++i)
        #pragma unroll
        for (int j = 0; j < TNJ; ++j)
            #pragma unroll
            for (int r = 0; r < 4; ++r) {
                int row = rBase + i * 16 + r;
                int col = cBase + j * 16;
                float v = acc[i][j][r];
                size_t o = cOff + (size_t)row * ldc + col;
                if (EPI == 0) Cf[o] = v;
                else if (EPI == 1) Cb[o] = f2b(v);
                else if (EPI == 2) {
                    v *= 0.125f;
                    if (col <= row - WIN_) v = -INFINITY;  // past-window mask only
                    Cf[o] = v;
                } else if (EPI == 3) {  // X1: + bias + residual
                    Cf[o] = v + bias[col] + res[(size_t)row * ldc + col];
                } else if (EPI == 4) {  // bf16 + bias (MoE h1)
                    Cb[o] = f2b(v + bias[col]);
                } else if (EPI == 5) {  // MoE out, first expert
                    Cf[o] = res[o] + coef[row] * (v + bias[col]);
                } else {                // MoE out, accumulate
                    Cf[o] += coef[row] * (v + bias[col]);
                }
            }
}

// ============================================================================
// Dual TN GEMM: p = swish(A@B1^T + bs; beta) * (A@B2^T + bg), bf16 out.
// A bf16 [M][K]; B1,B2 bf16 [N][K] (pre-transposed weights). TILE 128x64 (x2).
// ============================================================================
__global__ __launch_bounds__(256) void gemm_tn_dual(
    const u16* __restrict__ A, const u16* __restrict__ B1,
    const u16* __restrict__ B2, const float* __restrict__ bs,
    const float* __restrict__ bg, const float* __restrict__ betaP,
    u16* __restrict__ P, int K, int lda, int ldb, int ldc)
{
    __shared__ u16 As[128][40];
    __shared__ u16 B1s[64][40];
    __shared__ u16 B2s[64][40];
    int tid = threadIdx.x;
    const u16* Ap  = A  + (size_t)blockIdx.y * 128 * lda;
    const u16* B1p = B1 + (size_t)blockIdx.x * 64 * ldb;
    const u16* B2p = B2 + (size_t)blockIdx.x * 64 * ldb;

    f32x4 a1[4][2], a2[4][2];
    #pragma unroll
    for (int i = 0; i < 4; ++i)
        #pragma unroll
        for (int j = 0; j < 2; ++j) {
            a1[i][j] = (f32x4){0.f, 0.f, 0.f, 0.f};
            a2[i][j] = (f32x4){0.f, 0.f, 0.f, 0.f};
        }

    int lane = tid & 63, w = tid >> 6;
    int wr = (w >> 1) * 64, wc = (w & 1) * 32;
    int fm = lane & 15, fk = (lane >> 4) * 8;

    for (int k0 = 0; k0 < K; k0 += 32) {
        {   int r = tid >> 1, hf = (tid & 1) * 16;
            const u16* s = Ap + (size_t)r * lda + k0 + hf;
            *(float4*)&As[r][hf]     = *(const float4*)s;
            *(float4*)&As[r][hf + 8] = *(const float4*)(s + 8);
        }
        {   int r = tid >> 2, hf = (tid & 3) * 8;
            *(float4*)&B1s[r][hf] = *(const float4*)(B1p + (size_t)r * ldb + k0 + hf);
            *(float4*)&B2s[r][hf] = *(const float4*)(B2p + (size_t)r * ldb + k0 + hf);
        }
        __syncthreads();
        short8 af[4], b1f[2], b2f[2];
        #pragma unroll
        for (int i = 0; i < 4; ++i) af[i] = *(const short8*)&As[wr + i * 16 + fm][fk];
        #pragma unroll
        for (int j = 0; j < 2; ++j) {
            b1f[j] = *(const short8*)&B1s[wc + j * 16 + fm][fk];
            b2f[j] = *(const short8*)&B2s[wc + j * 16 + fm][fk];
        }
        #pragma unroll
        for (int i = 0; i < 4; ++i)
            #pragma unroll
            for (int j = 0; j < 2; ++j) {
                a1[i][j] = __builtin_amdgcn_mfma_f32_16x16x32_bf16(af[i], b1f[j], a1[i][j], 0, 0, 0);
                a2[i][j] = __builtin_amdgcn_mfma_f32_16x16x32_bf16(af[i], b2f[j], a2[i][j], 0, 0, 0);
            }
        __syncthreads();
    }

    float beta = betaP[0];
    int rBase = blockIdx.y * 128 + wr + (lane >> 4) * 4;
    int cBase = blockIdx.x * 64 + wc + fm;
    #pragma unroll
    for (int i = 0; i < 4; ++i)
        #pragma unroll
        for (int j = 0; j < 2; ++j)
            #pragma unroll
            for (int r = 0; r < 4; ++r) {
                int row = rBase + i * 16 + r;
                int col = cBase + j * 16;
                float sx = a1[i][j][r] + bs[col];
                float gl = a2[i][j][r] + bg[col];
                float sw = sx / (1.f + expf(-beta * sx));
                P[(size_t)row * ldc + col] = f2b(sw * gl);
            }
}

// ============================================================================
// Weight transpose: f32 [K][N] -> bf16 [N][K], LDS-tiled 64x64.
// Coalesced f32 reads, coalesced bf16 writes, 2-way (free) LDS banking.
// ============================================================================
__global__ __launch_bounds__(256) void transpose_w(
    const float* __restrict__ W, u16* __restrict__ out, int K, int N)
{
    __shared__ u16 Ls[64][66];
    int n0 = blockIdx.x * 64, k0 = blockIdx.y * 64;
    int tid = threadIdx.x;
    #pragma unroll
    for (int i = 0; i < 16; ++i) {
        int idx = tid + i * 256;
        int r = idx >> 6, c = idx & 63;           // r=k-local, c=n-local
        Ls[r][c] = f2b(W[(size_t)(k0 + r) * N + n0 + c]);
    }
    __syncthreads();
    #pragma unroll
    for (int i = 0; i < 16; ++i) {
        int idx = tid + i * 256;
        int n = idx >> 6, k = idx & 63;
        out[(size_t)(n0 + n) * K + k0 + k] = Ls[k][n];
    }
}

// ============================================================================
// Small kernels
// ============================================================================
// LayerNorm (ddof=1): out bf16 always; optional f32 copy.
__global__ __launch_bounds__(256) void ln_kernel(
    const float* __restrict__ x, const float* __restrict__ g,
    const float* __restrict__ b, u16* __restrict__ outB,
    float* __restrict__ outF, int wantF)
{
    int row = blockIdx.x;
    int tid = threadIdx.x;
    __shared__ float rs[256], rq[256];
    const float* xp = x + (size_t)row * C_;
    float s = 0.f, q = 0.f;
    for (int c = tid; c < C_; c += 256) {
        float v = xp[c];
        s += v; q += v * v;
    }
    rs[tid] = s; rq[tid] = q; __syncthreads();
    for (int off = 128; off > 0; off >>= 1) {
        if (tid < off) { rs[tid] += rs[tid + off]; rq[tid] += rq[tid + off]; }
        __syncthreads();
    }
    float mean = rs[0] * (1.f / C_);
    float var  = (rq[0] - (float)C_ * mean * mean) * (1.f / (C_ - 1));
    float inv  = rsqrtf(var + 1e-5f);
    for (int c = tid; c < C_; c += 256) {
        float v = (xp[c] - mean) * inv * g[c] + b[c];
        outB[(size_t)row * C_ + c] = f2b(v);
        if (wantF) outF[(size_t)row * C_ + c] = v;
    }
}

// Wk/Wv: f32 [H][C][D] -> bf16 [hd][c]
__global__ __launch_bounds__(256) void prep_whcd(const float* __restrict__ W, u16* __restrict__ out) {
    int idx = blockIdx.x * 256 + threadIdx.x;
    int hd = idx >> 10, c = idx & 1023;
    out[idx] = f2b(W[((size_t)(hd >> 6) * C_ + c) * 64 + (hd & 63)]);
}
// Wq summed over q: f32 [H][2][C][D] -> bf16 [hd][c]
__global__ __launch_bounds__(256) void prep_wq(const float* __restrict__ W, u16* __restrict__ out) {
    int idx = blockIdx.x * 256 + threadIdx.x;
    int hd = idx >> 10, c = idx & 1023;
    int h = hd >> 6, d = hd & 63;
    size_t i0 = (((size_t)h * 2 + 0) * C_ + c) * 64 + d;
    size_t i1 = (((size_t)h * 2 + 1) * C_ + c) * 64 + d;
    out[idx] = f2b(W[i0] + W[i1]);
}
// Wp: f32 [K][N] -> bf16 [N][K]
__global__ __launch_bounds__(256) void prep_wp(const float* __restrict__ W, u16* __restrict__ out) {
    int idx = blockIdx.x * 256 + threadIdx.x;
    int n = idx >> 10, k = idx & 1023;
    out[idx] = f2b(W[(size_t)k * C_ + n]);
}
// KrT[hb][s][d] = Kbf[(b*1024 + d*16 + (s>>6))*1024 + h*64 + (s&63)]
__global__ __launch_bounds__(256) void prep_krt(const u16* __restrict__ Kbf, u16* __restrict__ out) {
    int idx = blockIdx.x * 256 + threadIdx.x;
    int hb = idx >> 16, rem = idx & 65535;
    int s = rem >> 6, d = rem & 63;
    int h = hb >> 1, b = hb & 1;
    out[idx] = Kbf[((size_t)(b * 1024 + d * 16 + (s >> 6))) * 1024 + h * 64 + (s & 63)];
}
// VT[hb][d][s] = Vbf[(b*1024+s)*1024 + h*64 + d]
__global__ __launch_bounds__(256) void prep_vt(const u16* __restrict__ Vbf, u16* __restrict__ out) {
    int idx = blockIdx.x * 256 + threadIdx.x;
    int hb = idx >> 16, rem = idx & 65535;
    int d = rem >> 10, s = rem & 1023;
    int h = hb >> 1, b = hb & 1;
    out[idx] = Vbf[((size_t)(b * 1024 + s)) * 1024 + h * 64 + d];
}

// Row softmax over 1024 f32, in-place write as bf16 into row start.
__global__ __launch_bounds__(256) void softmax_rows(float* __restrict__ sc) {
    float* rp = sc + (size_t)blockIdx.x * 1024;
    int tid = threadIdx.x;
    float4 v = *(float4*)(rp + tid * 4);
    __shared__ float red[256];
    float mx = fmaxf(fmaxf(v.x, v.y), fmaxf(v.z, v.w));
    red[tid] = mx; __syncthreads();
    for (int off = 128; off > 0; off >>= 1) {
        if (tid < off) red[tid] = fmaxf(red[tid], red[tid + off]);
        __syncthreads();
    }
    mx = red[0]; __syncthreads();
    float e0 = expf(v.x - mx), e1 = expf(v.y - mx), e2 = expf(v.z - mx), e3 = expf(v.w - mx);
    red[tid] = e0 + e1 + e2 + e3; __syncthreads();
    for (int off = 128; off > 0; off >>= 1) {
        if (tid < off) red[tid] += red[tid + off];
        __syncthreads();
    }
    float inv = 1.f / red[0];
    u16* wp = (u16*)rp;
    wp[tid * 4 + 0] = f2b(e0 * inv);
    wp[tid * 4 + 1] = f2b(e1 * inv);
    wp[tid * 4 + 2] = f2b(e2 * inv);
    wp[tid * 4 + 3] = f2b(e3 * inv);
}

// Router: logits from f32 xn2, max + argmax per token.
__global__ __launch_bounds__(256) void router_kernel(
    const float* __restrict__ xn2, const float* __restrict__ Wg,
    const float* __restrict__ bgp, float* __restrict__ mOut, int* __restrict__ topiOut)
{
    int g = blockIdx.x;
    int tid = threadIdx.x;
    __shared__ float r0[256], r1[256];
    const float* xp = xn2 + (size_t)g * C_;
    float a0 = 0.f, a1 = 0.f;
    for (int c = tid; c < C_; c += 256) {
        float xv = xp[c];
        a0 += xv * Wg[c * 2 + 0];
        a1 += xv * Wg[c * 2 + 1];
    }
    r0[tid] = a0; r1[tid] = a1; __syncthreads();
    for (int off = 128; off > 0; off >>= 1) {
        if (tid < off) { r0[tid] += r0[tid + off]; r1[tid] += r1[tid + off]; }
        __syncthreads();
    }
    if (tid == 0) {
        float l0 = r0[0] + bgp[0];
        float l1 = r1[0] + bgp[1];
        topiOut[g] = (l1 > l0) ? 1 : 0;
        mOut[g] = fmaxf(l0, l1);
    }
}

// Softmax of max-logit over TOKEN axis (faithful bug) -> per-expert coef.
__global__ __launch_bounds__(256) void gatecoef_kernel(
    const float* __restrict__ m, const int* __restrict__ topi, float* __restrict__ coef)
{
    int b = blockIdx.x;
    int tid = threadIdx.x;
    __shared__ float red[256];
    const float* mp = m + (size_t)b * T_;
    float mx = -INFINITY;
    for (int t = tid; t < T_; t += 256) mx = fmaxf(mx, mp[t]);
    red[tid] = mx; __syncthreads();
    for (int off = 128; off > 0; off >>= 1) {
        if (tid < off) red[tid] = fmaxf(red[tid], red[tid + off]);
        __syncthreads();
    }
    mx = red[0]; __syncthreads();
    float s = 0.f;
    for (int t = tid; t < T_; t += 256) s += expf(mp[t] - mx);
    red[tid] = s; __syncthreads();
    for (int off = 128; off > 0; off >>= 1) {
        if (tid < off) red[tid] += red[tid + off];
        __syncthreads();
    }
    float inv = 1.f / red[0];
    for (int t = tid; t < T_; t += 256) {
        int g = b * T_ + t;
        float wv = expf(mp[t] - mx) * inv;
        int e = topi[g];
        coef[g]       = (e == 0) ? wv : 0.f;
        coef[BT_ + g] = (e == 1) ? wv : 0.f;
    }
}

// ============================================================================
// Host
// ============================================================================
extern "C" void kernel_launch(void* const* d_in, const int* in_sizes, int n_in,
                              void* d_out, int out_size, void* d_ws, size_t ws_size,
                              hipStream_t stream)
{
    const float* x    = (const float*)d_in[0];
    const float* Wq   = (const float*)d_in[1];
    const float* Wk   = (const float*)d_in[2];
    const float* Wv   = (const float*)d_in[3];
    const float* Wp   = (const float*)d_in[4];
    const float* bp   = (const float*)d_in[5];
    const float* ln1g = (const float*)d_in[6];
    const float* ln1b = (const float*)d_in[7];
    const float* ln2g = (const float*)d_in[8];
    const float* ln2b = (const float*)d_in[9];
    const float* Wg   = (const float*)d_in[10];
    const float* bg   = (const float*)d_in[11];
    const float* Ew1  = (const float*)d_in[12];
    const float* Eb1  = (const float*)d_in[13];
    const float* Ews  = (const float*)d_in[14];
    const float* Ebs  = (const float*)d_in[15];
    const float* Ebeta= (const float*)d_in[16];
    const float* Ewg  = (const float*)d_in[17];
    const float* Ebg  = (const float*)d_in[18];
    const float* Ew2  = (const float*)d_in[19];
    const float* Eb2  = (const float*)d_in[20];
    float* out = (float*)d_out;

    char* ws = (char*)d_ws;
    const size_t MB = 1024 * 1024;
    // Phase-A layout (offsets in bytes); phase-B aliases dead regions.
    u16*  xnbf   = (u16*) (ws + 0);        // 4 MB   (later: xn2bf)
    u16*  WqsT   = (u16*) (ws + 4*MB);     // 2 MB   (phase-B: W1T/W2T)
    u16*  WkT    = (u16*) (ws + 6*MB);     // 2 MB
    u16*  WvT    = (u16*) (ws + 8*MB);     // 2 MB
    u16*  WpT    = (u16*) (ws + 10*MB);    // 2 MB
    u16*  Qbf    = (u16*) (ws + 12*MB);    // 4 MB   (MoE: p 12-28)
    u16*  Kbf    = (u16*) (ws + 16*MB);    // 4 MB
    u16*  Vbf    = (u16*) (ws + 20*MB);    // 4 MB
    u16*  KrT    = (u16*) (ws + 24*MB);    // 4 MB
    u16*  VT     = (u16*) (ws + 28*MB);    // 4 MB   (later: xn2f 28-36)
    u16*  Obf    = (u16*) (ws + 32*MB);    // 4 MB
    float* x1    = (float*)(ws + 36*MB);   // 8 MB
    float* sc    = (float*)(ws + 44*MB);   // 16.78 MB scores chunk (MoE: h1 44-60)
    float* mbuf  = (float*)(ws + 61*MB);   // 8 KB
    int*   topi  = (int*)  (ws + 61*MB + 16*1024);
    float* coef  = (float*)(ws + 61*MB + 32*1024);  // [2][2048]
    // Phase-B aliases
    u16*  xn2bf  = (u16*) (ws + 0);
    float* xn2f  = (float*)(ws + 28*MB);
    u16*  h1     = (u16*) (ws + 44*MB);    // 16 MB [2048][4096]
    u16*  pbuf   = (u16*) (ws + 12*MB);    // 16 MB [2048][4096]
    // Phase-B bf16 transposed expert weights
    u16*  W1T    = (u16*) (ws + 4*MB);     // 8 MB [4096][1024] (dead prep region)
    u16*  W2T    = (u16*) (ws + 4*MB);     // 8 MB [1024][4096] (sequenced after W1T)
    u16*  WsT    = (u16*) (ws + 62*MB);    // 32 MB [4096][4096]
    u16*  WgT    = (u16*) (ws + 94*MB);    // 32 MB [4096][4096]  -> peak ws = 126 MB

    // --- 1. LN1 -> bf16 ---
    ln_kernel<<<BT_, 256, 0, stream>>>(x, ln1g, ln1b, xnbf, nullptr, 0);

    // --- 2. weight prep ---
    prep_whcd<<<C_*C_/256, 256, 0, stream>>>(Wk, WkT);
    prep_whcd<<<C_*C_/256, 256, 0, stream>>>(Wv, WvT);
    prep_wq  <<<C_*C_/256, 256, 0, stream>>>(Wq, WqsT);
    prep_wp  <<<C_*C_/256, 256, 0, stream>>>(Wp, WpT);

    // --- 3. Q/K/V projections (TN, bf16 out) ---
    {
        dim3 grid(16, 16, 1);
        gemm_tn<2,1><<<grid, 256, 0, stream>>>(xnbf, WqsT, nullptr, Qbf, nullptr, nullptr, nullptr,
            C_, C_, C_, C_, 0, 0,0,0, 0,0, 0,0,0);
        gemm_tn<2,1><<<grid, 256, 0, stream>>>(xnbf, WkT, nullptr, Kbf, nullptr, nullptr, nullptr,
            C_, C_, C_, C_, 0, 0,0,0, 0,0, 0,0,0);
        gemm_tn<2,1><<<grid, 256, 0, stream>>>(xnbf, WvT, nullptr, Vbf, nullptr, nullptr, nullptr,
            C_, C_, C_, C_, 0, 0,0,0, 0,0, 0,0,0);
    }
    prep_krt<<<H_*B_*T_*64/256, 256, 0, stream>>>(Kbf, KrT);
    prep_vt <<<H_*B_*T_*64/256, 256, 0, stream>>>(Vbf, VT);

    // --- 4. attention in hb-chunks of G_ ---
    for (int chunk = 0; chunk < (H_*B_)/G_; ++chunk) {
        int hb0 = chunk * G_;
        // scores = Q·KrT^T * 0.125, window mask; f32 [G][1024][1024]
        gemm_tn<4,2><<<dim3(8, 8, G_), 256, 0, stream>>>(
            Qbf, KrT, sc, nullptr, nullptr, nullptr, nullptr,
            64, C_, 64, 1024, hb0,
            /*aCz*/0, /*aCb*/1048576, /*aCh*/64,
            /*bCb*/65536, /*bCh*/131072,
            /*cCz*/1048576, 0, 0);
        // softmax rows, in-place -> bf16
        softmax_rows<<<G_*1024, 256, 0, stream>>>(sc);
        // O = W·VT^T -> Obf[b*T+t][h*64+d]
        gemm_tn<2,1><<<dim3(1, 8, G_), 256, 0, stream>>>(
            (u16*)sc, VT, nullptr, Obf, nullptr, nullptr, nullptr,
            1024, 2048, 1024, 1024, hb0,
            /*aCz*/2097152, 0, 0,
            /*bCb*/65536, /*bCh*/131072,
            /*cCz*/0, /*cCb*/1048576, /*cCh*/64);
    }

    // --- 5. x1 = x + Obf@WpT + bp ---
    gemm_tn<2,3><<<dim3(16, 16, 1), 256, 0, stream>>>(
        Obf, WpT, x1, nullptr, bp, x, nullptr,
        C_, C_, C_, C_, 0, 0,0,0, 0,0, 0,0,0);

    // --- 6. LN2 (f32 for router + bf16 for GEMMs) ---
    ln_kernel<<<BT_, 256, 0, stream>>>(x1, ln2g, ln2b, xn2bf, xn2f, 1);

    // --- 7. router + gate ---
    router_kernel<<<BT_, 256, 0, stream>>>(xn2f, Wg, bg, mbuf, topi);
    gatecoef_kernel<<<B_, 256, 0, stream>>>(mbuf, topi, coef);

    // --- 8. MoE: pre-transpose weights to bf16 [N][K], all GEMMs on TN path ---
    for (int e = 0; e < E_; ++e) {
        // W1T = Ew1[e]^T bf16 [4096][1024]
        transpose_w<<<dim3(NH_/64, C_/64), 256, 0, stream>>>(
            Ew1 + (size_t)e * C_ * NH_, W1T, C_, NH_);
        // h1 = xn2@Ew1[e] + Eb1[e] -> bf16 [2048][4096]
        gemm_tn<4,4><<<dim3(NH_/128, 16), 256, 0, stream>>>(
            xn2bf, W1T, nullptr, h1, Eb1 + (size_t)e * NH_, nullptr, nullptr,
            C_, C_, C_, NH_, 0, 0,0,0, 0,0, 0,0,0);
        // WsT/WgT = Ews[e]^T / Ewg[e]^T bf16 [4096][4096]
        transpose_w<<<dim3(NH_/64, NH_/64), 256, 0, stream>>>(
            Ews + (size_t)e * NH_ * NH_, WsT, NH_, NH_);
        transpose_w<<<dim3(NH_/64, NH_/64), 256, 0, stream>>>(
            Ewg + (size_t)e * NH_ * NH_, WgT, NH_, NH_);
        // p = swish(h1@Ews+Ebs) * (h1@Ewg+Ebg) -> bf16
        gemm_tn_dual<<<dim3(NH_/64, 16), 256, 0, stream>>>(
            h1, WsT, WgT, Ebs + (size_t)e * NH_, Ebg + (size_t)e * NH_, Ebeta + e,
            pbuf, NH_, NH_, NH_, NH_);
        // W2T = Ew2[e]^T bf16 [1024][4096]
        transpose_w<<<dim3(C_/64, NH_/64), 256, 0, stream>>>(
            Ew2 + (size_t)e * NH_ * C_, W2T, NH_, C_);
        // out (+)= coef_e * (p@Ew2[e] + Eb2[e])  (+ x1 on first pass)
        if (e == 0)
            gemm_tn<2,5><<<dim3(C_/64, 16), 256, 0, stream>>>(
                pbuf, W2T, out, nullptr, Eb2, x1, coef + 0 * BT_,
                NH_, NH_, NH_, C_, 0, 0,0,0, 0,0, 0,0,0);
        else
            gemm_tn<2,6><<<dim3(C_/64, 16), 256, 0, stream>>>(
                pbuf, W2T, out, nullptr, Eb2 + (size_t)e * C_, nullptr, coef + (size_t)e * BT_,
                NH_, NH_, NH_, C_, 0, 0,0,0, 0,0, 0,0,0);
    }
}

// Round 2
// 1441.935 us; speedup vs baseline: 1.1477x; 1.1007x over previous
//
#include <hip/hip_runtime.h>
#include <hip/hip_bf16.h>
#include <cmath>

#define B_    2
#define T_    1024
#define BT_   2048
#define C_    1024
#define H_    16
#define NH_   4096
#define E_    2
#define WIN_  256
#define G_    4          // attention hb-chunk size

typedef unsigned short u16;
typedef __attribute__((ext_vector_type(8))) short short8;
typedef __attribute__((ext_vector_type(4))) float f32x4;

__device__ __forceinline__ u16 f2b(float f) {
    __hip_bfloat16 h = __float2bfloat16(f);
    return *(u16*)&h;
}
__device__ __forceinline__ float b2f(u16 u) {
    __hip_bfloat16 h; *(u16*)&h = u;
    return __bfloat162float(h);
}

// async global->LDS, 16B per lane; lds base must be wave-uniform (HW adds lane*16)
__device__ __forceinline__ void gl_lds16(const u16* g, u16* l) {
    __builtin_amdgcn_global_load_lds(
        (const __attribute__((address_space(1))) unsigned int*)g,
        (__attribute__((address_space(3))) unsigned int*)l, 16, 0, 0);
}

// ============================================================================
// MFMA GEMM, TN path: A bf16 [M][K] (lda), B bf16 [N][K] (ldb).
// TILE: 128 x (TNJ*32), BK=32. 4 waves in 2x2. Batched via z with offset coefs.
// Staging: global_load_lds w16, linear LDS, XOR slot-swizzle (slot ^= (row>>1)&3)
//   applied on SOURCE addr at write and on READ offset (involution, rule #21).
// EPI: 0=f32, 1=bf16, 2=scores(scale+window-mask,f32), 3=x1(bias+res,f32),
//      4=bf16+bias, 5=f32 res+coef*(v+bias), 6=f32 +=coef*(v+bias)
// ============================================================================
template<int TNJ, int EPI>
__global__ __launch_bounds__(256) void gemm_tn(
    const u16* __restrict__ A, const u16* __restrict__ B,
    float* __restrict__ Cf, u16* __restrict__ Cb,
    const float* __restrict__ bias, const float* __restrict__ res,
    const float* __restrict__ coef,
    int K, int lda, int ldb, int ldc,
    int hb0, long aCz, long aCb, long aCh,
    long bCb, long bCh, long cCz, long cCb, long cCh)
{
    constexpr int TN = TNJ * 32;
    constexpr int NINST = 8 + TN / 16;   // 1KB-instructions per K-step
    constexpr int NPW = NINST / 4;       // per wave
    __shared__ alignas(16) u16 AsL[128 * 32];
    __shared__ alignas(16) u16 BsL[TN * 32];
    int tid = threadIdx.x;
    int z = blockIdx.z;
    int hb = hb0 + z;
    int hh = hb >> 1, bb = hb & 1;
    const u16* Ap = A + aCz * z + aCb * bb + aCh * hh + (size_t)blockIdx.y * 128 * lda;
    const u16* Bp = B + bCb * bb + bCh * hh + (size_t)blockIdx.x * TN * ldb;
    size_t cOff = (size_t)(cCz * z + cCb * bb + cCh * hh);

    int lane = tid & 63, w = tid >> 6;
    int wr = (w >> 1) * 64, wc = (w & 1) * (TNJ * 16);
    int fm = lane & 15;

    // --- staging precompute: per-wave instructions, pre-swizzled global src ---
    const u16* gsrc[NPW];
    u16* ldst[NPW];
    #pragma unroll
    for (int ii = 0; ii < NPW; ++ii) {
        int inst = w * NPW + ii;
        int lrow = lane >> 2;
        int sx = lane & 3;
        if (inst < 8) {
            int row = inst * 16 + lrow;
            gsrc[ii] = Ap + (size_t)row * lda + ((sx ^ ((row >> 1) & 3)) * 8);
            ldst[ii] = AsL + inst * 512;
        } else {
            int row = (inst - 8) * 16 + lrow;
            gsrc[ii] = Bp + (size_t)row * ldb + ((sx ^ ((row >> 1) & 3)) * 8);
            ldst[ii] = BsL + (inst - 8) * 512;
        }
    }
    // --- fragment read offsets (u16 units), same XOR swizzle ---
    int aoff[4], boff[TNJ];
    #pragma unroll
    for (int i = 0; i < 4; ++i) {
        int r = wr + i * 16 + fm;
        aoff[i] = r * 32 + (((lane >> 4) ^ ((r >> 1) & 3)) * 8);
    }
    #pragma unroll
    for (int j = 0; j < TNJ; ++j) {
        int r = wc + j * 16 + fm;
        boff[j] = r * 32 + (((lane >> 4) ^ ((r >> 1) & 3)) * 8);
    }

    f32x4 acc[4][TNJ];
    #pragma unroll
    for (int i = 0; i < 4; ++i)
        #pragma unroll
        for (int j = 0; j < TNJ; ++j)
            acc[i][j] = (f32x4){0.f, 0.f, 0.f, 0.f};

    for (int k0 = 0; k0 < K; k0 += 32) {
        #pragma unroll
        for (int ii = 0; ii < NPW; ++ii)
            gl_lds16(gsrc[ii] + k0, ldst[ii]);
        __syncthreads();   // compiler drains vmcnt before barrier
        short8 af[4], bf[TNJ];
        #pragma unroll
        for (int i = 0; i < 4; ++i) af[i] = *(const short8*)(AsL + aoff[i]);
        #pragma unroll
        for (int j = 0; j < TNJ; ++j) bf[j] = *(const short8*)(BsL + boff[j]);
        #pragma unroll
        for (int i = 0; i < 4; ++i)
            #pragma unroll
            for (int j = 0; j < TNJ; ++j)
                acc[i][j] = __builtin_amdgcn_mfma_f32_16x16x32_bf16(af[i], bf[j], acc[i][j], 0, 0, 0);
        __syncthreads();
    }

    int rBase = blockIdx.y * 128 + wr + (lane >> 4) * 4;
    int cBase = blockIdx.x * TN + wc + fm;
    #pragma unroll
    for (int i = 0; i < 4; ++i)
        #pragma unroll
        for (int j = 0; j < TNJ; ++j)
            #pragma unroll
            for (int r = 0; r < 4; ++r) {
                int row = rBase + i * 16 + r;
                int col = cBase + j * 16;
                float v = acc[i][j][r];
                size_t o = cOff + (size_t)row * ldc + col;
                if (EPI == 0) Cf[o] = v;
                else if (EPI == 1) Cb[o] = f2b(v);
                else if (EPI == 2) {
                    v *= 0.125f;
                    if (col <= row - WIN_) v = -INFINITY;  // past-window mask only
                    Cf[o] = v;
                } else if (EPI == 3) {  // X1: + bias + residual
                    Cf[o] = v + bias[col] + res[(size_t)row * ldc + col];
                } else if (EPI == 4) {  // bf16 + bias (MoE h1)
                    Cb[o] = f2b(v + bias[col]);
                } else if (EPI == 5) {  // MoE out, first expert
                    Cf[o] = res[o] + coef[row] * (v + bias[col]);
                } else {                // MoE out, accumulate
                    Cf[o] += coef[row] * (v + bias[col]);
                }
            }
}

// ============================================================================
// Dual TN GEMM: p = swish(A@B1^T + bs; beta) * (A@B2^T + bg), bf16 out.
// A bf16 [M][K]; B1,B2 bf16 [N][K]. TILE 128x64 (x2 B). Same staging scheme.
// ============================================================================
__global__ __launch_bounds__(256) void gemm_tn_dual(
    const u16* __restrict__ A, const u16* __restrict__ B1,
    const u16* __restrict__ B2, const float* __restrict__ bs,
    const float* __restrict__ bg, const float* __restrict__ betaP,
    u16* __restrict__ P, int K, int lda, int ldb, int ldc)
{
    __shared__ alignas(16) u16 AsL[128 * 32];
    __shared__ alignas(16) u16 B1L[64 * 32];
    __shared__ alignas(16) u16 B2L[64 * 32];
    int tid = threadIdx.x;
    const u16* Ap  = A  + (size_t)blockIdx.y * 128 * lda;
    const u16* B1p = B1 + (size_t)blockIdx.x * 64 * ldb;
    const u16* B2p = B2 + (size_t)blockIdx.x * 64 * ldb;

    int lane = tid & 63, w = tid >> 6;
    int wr = (w >> 1) * 64, wc = (w & 1) * 32;
    int fm = lane & 15;

    // 16 instructions: 0-7 A, 8-11 B1, 12-15 B2 -> 4 per wave
    const u16* gsrc[4];
    u16* ldst[4];
    #pragma unroll
    for (int ii = 0; ii < 4; ++ii) {
        int inst = w * 4 + ii;
        int lrow = lane >> 2;
        int sx = lane & 3;
        if (inst < 8) {
            int row = inst * 16 + lrow;
            gsrc[ii] = Ap + (size_t)row * lda + ((sx ^ ((row >> 1) & 3)) * 8);
            ldst[ii] = AsL + inst * 512;
        } else if (inst < 12) {
            int row = (inst - 8) * 16 + lrow;
            gsrc[ii] = B1p + (size_t)row * ldb + ((sx ^ ((row >> 1) & 3)) * 8);
            ldst[ii] = B1L + (inst - 8) * 512;
        } else {
            int row = (inst - 12) * 16 + lrow;
            gsrc[ii] = B2p + (size_t)row * ldb + ((sx ^ ((row >> 1) & 3)) * 8);
            ldst[ii] = B2L + (inst - 12) * 512;
        }
    }
    int aoff[4], boff[2];
    #pragma unroll
    for (int i = 0; i < 4; ++i) {
        int r = wr + i * 16 + fm;
        aoff[i] = r * 32 + (((lane >> 4) ^ ((r >> 1) & 3)) * 8);
    }
    #pragma unroll
    for (int j = 0; j < 2; ++j) {
        int r = wc + j * 16 + fm;
        boff[j] = r * 32 + (((lane >> 4) ^ ((r >> 1) & 3)) * 8);
    }

    f32x4 a1[4][2], a2[4][2];
    #pragma unroll
    for (int i = 0; i < 4; ++i)
        #pragma unroll
        for (int j = 0; j < 2; ++j) {
            a1[i][j] = (f32x4){0.f, 0.f, 0.f, 0.f};
            a2[i][j] = (f32x4){0.f, 0.f, 0.f, 0.f};
        }

    for (int k0 = 0; k0 < K; k0 += 32) {
        #pragma unroll
        for (int ii = 0; ii < 4; ++ii)
            gl_lds16(gsrc[ii] + k0, ldst[ii]);
        __syncthreads();
        short8 af[4], b1f[2], b2f[2];
        #pragma unroll
        for (int i = 0; i < 4; ++i) af[i] = *(const short8*)(AsL + aoff[i]);
        #pragma unroll
        for (int j = 0; j < 2; ++j) {
            b1f[j] = *(const short8*)(B1L + boff[j]);
            b2f[j] = *(const short8*)(B2L + boff[j]);
        }
        #pragma unroll
        for (int i = 0; i < 4; ++i)
            #pragma unroll
            for (int j = 0; j < 2; ++j) {
                a1[i][j] = __builtin_amdgcn_mfma_f32_16x16x32_bf16(af[i], b1f[j], a1[i][j], 0, 0, 0);
                a2[i][j] = __builtin_amdgcn_mfma_f32_16x16x32_bf16(af[i], b2f[j], a2[i][j], 0, 0, 0);
            }
        __syncthreads();
    }

    float beta = betaP[0];
    int rBase = blockIdx.y * 128 + wr + (lane >> 4) * 4;
    int cBase = blockIdx.x * 64 + wc + fm;
    #pragma unroll
    for (int i = 0; i < 4; ++i)
        #pragma unroll
        for (int j = 0; j < 2; ++j)
            #pragma unroll
            for (int r = 0; r < 4; ++r) {
                int row = rBase + i * 16 + r;
                int col = cBase + j * 16;
                float sx = a1[i][j][r] + bs[col];
                float gl = a2[i][j][r] + bg[col];
                float sw = sx / (1.f + expf(-beta * sx));
                P[(size_t)row * ldc + col] = f2b(sw * gl);
            }
}

// ============================================================================
// Weight transpose: f32 [K][N] -> bf16 [N][K], LDS-tiled 64x64.
// ============================================================================
__global__ __launch_bounds__(256) void transpose_w(
    const float* __restrict__ W, u16* __restrict__ out, int K, int N)
{
    __shared__ u16 Ls[64][66];
    int n0 = blockIdx.x * 64, k0 = blockIdx.y * 64;
    int tid = threadIdx.x;
    #pragma unroll
    for (int i = 0; i < 16; ++i) {
        int idx = tid + i * 256;
        int r = idx >> 6, c = idx & 63;           // r=k-local, c=n-local
        Ls[r][c] = f2b(W[(size_t)(k0 + r) * N + n0 + c]);
    }
    __syncthreads();
    #pragma unroll
    for (int i = 0; i < 16; ++i) {
        int idx = tid + i * 256;
        int n = idx >> 6, k = idx & 63;
        out[(size_t)(n0 + n) * K + k0 + k] = Ls[k][n];
    }
}

// ============================================================================
// Small kernels
// ============================================================================
// LayerNorm (ddof=1): out bf16 always; optional f32 copy.
__global__ __launch_bounds__(256) void ln_kernel(
    const float* __restrict__ x, const float* __restrict__ g,
    const float* __restrict__ b, u16* __restrict__ outB,
    float* __restrict__ outF, int wantF)
{
    int row = blockIdx.x;
    int tid = threadIdx.x;
    __shared__ float rs[256], rq[256];
    const float* xp = x + (size_t)row * C_;
    float s = 0.f, q = 0.f;
    for (int c = tid; c < C_; c += 256) {
        float v = xp[c];
        s += v; q += v * v;
    }
    rs[tid] = s; rq[tid] = q; __syncthreads();
    for (int off = 128; off > 0; off >>= 1) {
        if (tid < off) { rs[tid] += rs[tid + off]; rq[tid] += rq[tid + off]; }
        __syncthreads();
    }
    float mean = rs[0] * (1.f / C_);
    float var  = (rq[0] - (float)C_ * mean * mean) * (1.f / (C_ - 1));
    float inv  = rsqrtf(var + 1e-5f);
    for (int c = tid; c < C_; c += 256) {
        float v = (xp[c] - mean) * inv * g[c] + b[c];
        outB[(size_t)row * C_ + c] = f2b(v);
        if (wantF) outF[(size_t)row * C_ + c] = v;
    }
}

// Wk/Wv: f32 [H][C][D] -> bf16 [hd][c]
__global__ __launch_bounds__(256) void prep_whcd(const float* __restrict__ W, u16* __restrict__ out) {
    int idx = blockIdx.x * 256 + threadIdx.x;
    int hd = idx >> 10, c = idx & 1023;
    out[idx] = f2b(W[((size_t)(hd >> 6) * C_ + c) * 64 + (hd & 63)]);
}
// Wq summed over q: f32 [H][2][C][D] -> bf16 [hd][c]
__global__ __launch_bounds__(256) void prep_wq(const float* __restrict__ W, u16* __restrict__ out) {
    int idx = blockIdx.x * 256 + threadIdx.x;
    int hd = idx >> 10, c = idx & 1023;
    int h = hd >> 6, d = hd & 63;
    size_t i0 = (((size_t)h * 2 + 0) * C_ + c) * 64 + d;
    size_t i1 = (((size_t)h * 2 + 1) * C_ + c) * 64 + d;
    out[idx] = f2b(W[i0] + W[i1]);
}
// Wp: f32 [K][N] -> bf16 [N][K]
__global__ __launch_bounds__(256) void prep_wp(const float* __restrict__ W, u16* __restrict__ out) {
    int idx = blockIdx.x * 256 + threadIdx.x;
    int n = idx >> 10, k = idx & 1023;
    out[idx] = f2b(W[(size_t)k * C_ + n]);
}
// KrT[hb][s][d] = Kbf[(b*1024 + d*16 + (s>>6))*1024 + h*64 + (s&63)]
__global__ __launch_bounds__(256) void prep_krt(const u16* __restrict__ Kbf, u16* __restrict__ out) {
    int idx = blockIdx.x * 256 + threadIdx.x;
    int hb = idx >> 16, rem = idx & 65535;
    int s = rem >> 6, d = rem & 63;
    int h = hb >> 1, b = hb & 1;
    out[idx] = Kbf[((size_t)(b * 1024 + d * 16 + (s >> 6))) * 1024 + h * 64 + (s & 63)];
}
// VT[hb][d][s] = Vbf[(b*1024+s)*1024 + h*64 + d]
__global__ __launch_bounds__(256) void prep_vt(const u16* __restrict__ Vbf, u16* __restrict__ out) {
    int idx = blockIdx.x * 256 + threadIdx.x;
    int hb = idx >> 16, rem = idx & 65535;
    int d = rem >> 10, s = rem & 1023;
    int h = hb >> 1, b = hb & 1;
    out[idx] = Vbf[((size_t)(b * 1024 + s)) * 1024 + h * 64 + d];
}

// Row softmax over 1024 f32, in-place write as bf16 into row start.
__global__ __launch_bounds__(256) void softmax_rows(float* __restrict__ sc) {
    float* rp = sc + (size_t)blockIdx.x * 1024;
    int tid = threadIdx.x;
    float4 v = *(float4*)(rp + tid * 4);
    __shared__ float red[256];
    float mx = fmaxf(fmaxf(v.x, v.y), fmaxf(v.z, v.w));
    red[tid] = mx; __syncthreads();
    for (int off = 128; off > 0; off >>= 1) {
        if (tid < off) red[tid] = fmaxf(red[tid], red[tid + off]);
        __syncthreads();
    }
    mx = red[0]; __syncthreads();
    float e0 = expf(v.x - mx), e1 = expf(v.y - mx), e2 = expf(v.z - mx), e3 = expf(v.w - mx);
    red[tid] = e0 + e1 + e2 + e3; __syncthreads();
    for (int off = 128; off > 0; off >>= 1) {
        if (tid < off) red[tid] += red[tid + off];
        __syncthreads();
    }
    float inv = 1.f / red[0];
    u16* wp = (u16*)rp;
    wp[tid * 4 + 0] = f2b(e0 * inv);
    wp[tid * 4 + 1] = f2b(e1 * inv);
    wp[tid * 4 + 2] = f2b(e2 * inv);
    wp[tid * 4 + 3] = f2b(e3 * inv);
}

// Router: logits from f32 xn2, max + argmax per token.
__global__ __launch_bounds__(256) void router_kernel(
    const float* __restrict__ xn2, const float* __restrict__ Wg,
    const float* __restrict__ bgp, float* __restrict__ mOut, int* __restrict__ topiOut)
{
    int g = blockIdx.x;
    int tid = threadIdx.x;
    __shared__ float r0[256], r1[256];
    const float* xp = xn2 + (size_t)g * C_;
    float a0 = 0.f, a1 = 0.f;
    for (int c = tid; c < C_; c += 256) {
        float xv = xp[c];
        a0 += xv * Wg[c * 2 + 0];
        a1 += xv * Wg[c * 2 + 1];
    }
    r0[tid] = a0; r1[tid] = a1; __syncthreads();
    for (int off = 128; off > 0; off >>= 1) {
        if (tid < off) { r0[tid] += r0[tid + off]; r1[tid] += r1[tid + off]; }
        __syncthreads();
    }
    if (tid == 0) {
        float l0 = r0[0] + bgp[0];
        float l1 = r1[0] + bgp[1];
        topiOut[g] = (l1 > l0) ? 1 : 0;
        mOut[g] = fmaxf(l0, l1);
    }
}

// Softmax of max-logit over TOKEN axis (faithful bug) -> per-expert coef.
__global__ __launch_bounds__(256) void gatecoef_kernel(
    const float* __restrict__ m, const int* __restrict__ topi, float* __restrict__ coef)
{
    int b = blockIdx.x;
    int tid = threadIdx.x;
    __shared__ float red[256];
    const float* mp = m + (size_t)b * T_;
    float mx = -INFINITY;
    for (int t = tid; t < T_; t += 256) mx = fmaxf(mx, mp[t]);
    red[tid] = mx; __syncthreads();
    for (int off = 128; off > 0; off >>= 1) {
        if (tid < off) red[tid] = fmaxf(red[tid], red[tid + off]);
        __syncthreads();
    }
    mx = red[0]; __syncthreads();
    float s = 0.f;
    for (int t = tid; t < T_; t += 256) s += expf(mp[t] - mx);
    red[tid] = s; __syncthreads();
    for (int off = 128; off > 0; off >>= 1) {
        if (tid < off) red[tid] += red[tid + off];
        __syncthreads();
    }
    float inv = 1.f / red[0];
    for (int t = tid; t < T_; t += 256) {
        int g = b * T_ + t;
        float wv = expf(mp[t] - mx) * inv;
        int e = topi[g];
        coef[g]       = (e == 0) ? wv : 0.f;
        coef[BT_ + g] = (e == 1) ? wv : 0.f;
    }
}

// ============================================================================
// Host
// ============================================================================
extern "C" void kernel_launch(void* const* d_in, const int* in_sizes, int n_in,
                              void* d_out, int out_size, void* d_ws, size_t ws_size,
                              hipStream_t stream)
{
    const float* x    = (const float*)d_in[0];
    const float* Wq   = (const float*)d_in[1];
    const float* Wk   = (const float*)d_in[2];
    const float* Wv   = (const float*)d_in[3];
    const float* Wp   = (const float*)d_in[4];
    const float* bp   = (const float*)d_in[5];
    const float* ln1g = (const float*)d_in[6];
    const float* ln1b = (const float*)d_in[7];
    const float* ln2g = (const float*)d_in[8];
    const float* ln2b = (const float*)d_in[9];
    const float* Wg   = (const float*)d_in[10];
    const float* bg   = (const float*)d_in[11];
    const float* Ew1  = (const float*)d_in[12];
    const float* Eb1  = (const float*)d_in[13];
    const float* Ews  = (const float*)d_in[14];
    const float* Ebs  = (const float*)d_in[15];
    const float* Ebeta= (const float*)d_in[16];
    const float* Ewg  = (const float*)d_in[17];
    const float* Ebg  = (const float*)d_in[18];
    const float* Ew2  = (const float*)d_in[19];
    const float* Eb2  = (const float*)d_in[20];
    float* out = (float*)d_out;

    char* ws = (char*)d_ws;
    const size_t MB = 1024 * 1024;
    // Phase-A layout (offsets in bytes); phase-B aliases dead regions.
    u16*  xnbf   = (u16*) (ws + 0);        // 4 MB   (later: xn2bf)
    u16*  WqsT   = (u16*) (ws + 4*MB);     // 2 MB   (phase-B: W1T/W2T)
    u16*  WkT    = (u16*) (ws + 6*MB);     // 2 MB
    u16*  WvT    = (u16*) (ws + 8*MB);     // 2 MB
    u16*  WpT    = (u16*) (ws + 10*MB);    // 2 MB
    u16*  Qbf    = (u16*) (ws + 12*MB);    // 4 MB   (MoE: p 12-28)
    u16*  Kbf    = (u16*) (ws + 16*MB);    // 4 MB
    u16*  Vbf    = (u16*) (ws + 20*MB);    // 4 MB
    u16*  KrT    = (u16*) (ws + 24*MB);    // 4 MB
    u16*  VT     = (u16*) (ws + 28*MB);    // 4 MB   (later: xn2f 28-36)
    u16*  Obf    = (u16*) (ws + 32*MB);    // 4 MB
    float* x1    = (float*)(ws + 36*MB);   // 8 MB
    float* sc    = (float*)(ws + 44*MB);   // 16.78 MB scores chunk (MoE: h1 44-60)
    float* mbuf  = (float*)(ws + 61*MB);   // 8 KB
    int*   topi  = (int*)  (ws + 61*MB + 16*1024);
    float* coef  = (float*)(ws + 61*MB + 32*1024);  // [2][2048]
    // Phase-B aliases
    u16*  xn2bf  = (u16*) (ws + 0);
    float* xn2f  = (float*)(ws + 28*MB);
    u16*  h1     = (u16*) (ws + 44*MB);    // 16 MB [2048][4096]
    u16*  pbuf   = (u16*) (ws + 12*MB);    // 16 MB [2048][4096]
    // Phase-B bf16 transposed expert weights
    u16*  W1T    = (u16*) (ws + 4*MB);     // 8 MB [4096][1024] (dead prep region)
    u16*  W2T    = (u16*) (ws + 4*MB);     // 8 MB [1024][4096] (sequenced after W1T)
    u16*  WsT    = (u16*) (ws + 62*MB);    // 32 MB [4096][4096]
    u16*  WgT    = (u16*) (ws + 94*MB);    // 32 MB [4096][4096]  -> peak ws = 126 MB

    // --- 1. LN1 -> bf16 ---
    ln_kernel<<<BT_, 256, 0, stream>>>(x, ln1g, ln1b, xnbf, nullptr, 0);

    // --- 2. weight prep ---
    prep_whcd<<<C_*C_/256, 256, 0, stream>>>(Wk, WkT);
    prep_whcd<<<C_*C_/256, 256, 0, stream>>>(Wv, WvT);
    prep_wq  <<<C_*C_/256, 256, 0, stream>>>(Wq, WqsT);
    prep_wp  <<<C_*C_/256, 256, 0, stream>>>(Wp, WpT);

    // --- 3. Q/K/V projections (TN, bf16 out) ---
    {
        dim3 grid(16, 16, 1);
        gemm_tn<2,1><<<grid, 256, 0, stream>>>(xnbf, WqsT, nullptr, Qbf, nullptr, nullptr, nullptr,
            C_, C_, C_, C_, 0, 0,0,0, 0,0, 0,0,0);
        gemm_tn<2,1><<<grid, 256, 0, stream>>>(xnbf, WkT, nullptr, Kbf, nullptr, nullptr, nullptr,
            C_, C_, C_, C_, 0, 0,0,0, 0,0, 0,0,0);
        gemm_tn<2,1><<<grid, 256, 0, stream>>>(xnbf, WvT, nullptr, Vbf, nullptr, nullptr, nullptr,
            C_, C_, C_, C_, 0, 0,0,0, 0,0, 0,0,0);
    }
    prep_krt<<<H_*B_*T_*64/256, 256, 0, stream>>>(Kbf, KrT);
    prep_vt <<<H_*B_*T_*64/256, 256, 0, stream>>>(Vbf, VT);

    // --- 4. attention in hb-chunks of G_ ---
    for (int chunk = 0; chunk < (H_*B_)/G_; ++chunk) {
        int hb0 = chunk * G_;
        // scores = Q·KrT^T * 0.125, window mask; f32 [G][1024][1024]
        gemm_tn<4,2><<<dim3(8, 8, G_), 256, 0, stream>>>(
            Qbf, KrT, sc, nullptr, nullptr, nullptr, nullptr,
            64, C_, 64, 1024, hb0,
            /*aCz*/0, /*aCb*/1048576, /*aCh*/64,
            /*bCb*/65536, /*bCh*/131072,
            /*cCz*/1048576, 0, 0);
        // softmax rows, in-place -> bf16
        softmax_rows<<<G_*1024, 256, 0, stream>>>(sc);
        // O = W·VT^T -> Obf[b*T+t][h*64+d]
        gemm_tn<2,1><<<dim3(1, 8, G_), 256, 0, stream>>>(
            (u16*)sc, VT, nullptr, Obf, nullptr, nullptr, nullptr,
            1024, 2048, 1024, 1024, hb0,
            /*aCz*/2097152, 0, 0,
            /*bCb*/65536, /*bCh*/131072,
            /*cCz*/0, /*cCb*/1048576, /*cCh*/64);
    }

    // --- 5. x1 = x + Obf@WpT + bp ---
    gemm_tn<2,3><<<dim3(16, 16, 1), 256, 0, stream>>>(
        Obf, WpT, x1, nullptr, bp, x, nullptr,
        C_, C_, C_, C_, 0, 0,0,0, 0,0, 0,0,0);

    // --- 6. LN2 (f32 for router + bf16 for GEMMs) ---
    ln_kernel<<<BT_, 256, 0, stream>>>(x1, ln2g, ln2b, xn2bf, xn2f, 1);

    // --- 7. router + gate ---
    router_kernel<<<BT_, 256, 0, stream>>>(xn2f, Wg, bg, mbuf, topi);
    gatecoef_kernel<<<B_, 256, 0, stream>>>(mbuf, topi, coef);

    // --- 8. MoE: pre-transposed bf16 weights, all GEMMs on TN path ---
    for (int e = 0; e < E_; ++e) {
        // W1T = Ew1[e]^T bf16 [4096][1024]
        transpose_w<<<dim3(NH_/64, C_/64), 256, 0, stream>>>(
            Ew1 + (size_t)e * C_ * NH_, W1T, C_, NH_);
        // h1 = xn2@Ew1[e] + Eb1[e] -> bf16 [2048][4096]
        gemm_tn<4,4><<<dim3(NH_/128, 16), 256, 0, stream>>>(
            xn2bf, W1T, nullptr, h1, Eb1 + (size_t)e * NH_, nullptr, nullptr,
            C_, C_, C_, NH_, 0, 0,0,0, 0,0, 0,0,0);
        // WsT/WgT = Ews[e]^T / Ewg[e]^T bf16 [4096][4096]
        transpose_w<<<dim3(NH_/64, NH_/64), 256, 0, stream>>>(
            Ews + (size_t)e * NH_ * NH_, WsT, NH_, NH_);
        transpose_w<<<dim3(NH_/64, NH_/64), 256, 0, stream>>>(
            Ewg + (size_t)e * NH_ * NH_, WgT, NH_, NH_);
        // p = swish(h1@Ews+Ebs) * (h1@Ewg+Ebg) -> bf16
        gemm_tn_dual<<<dim3(NH_/64, 16), 256, 0, stream>>>(
            h1, WsT, WgT, Ebs + (size_t)e * NH_, Ebg + (size_t)e * NH_, Ebeta + e,
            pbuf, NH_, NH_, NH_, NH_);
        // W2T = Ew2[e]^T bf16 [1024][4096]
        transpose_w<<<dim3(C_/64, NH_/64), 256, 0, stream>>>(
            Ew2 + (size_t)e * NH_ * C_, W2T, NH_, C_);
        // out (+)= coef_e * (p@Ew2[e] + Eb2[e])  (+ x1 on first pass)
        if (e == 0)
            gemm_tn<2,5><<<dim3(C_/64, 16), 256, 0, stream>>>(
                pbuf, W2T, out, nullptr, Eb2, x1, coef + 0 * BT_,
                NH_, NH_, NH_, C_, 0, 0,0,0, 0,0, 0,0,0);
        else
            gemm_tn<2,6><<<dim3(C_/64, 16), 256, 0, stream>>>(
                pbuf, W2T, out, nullptr, Eb2 + (size_t)e * C_, nullptr, coef + (size_t)e * BT_,
                NH_, NH_, NH_, C_, 0, 0,0,0, 0,0, 0,0,0);
    }
}

// Round 3
// 1186.345 us; speedup vs baseline: 1.3949x; 1.2154x over previous
//
#include <hip/hip_runtime.h>
#include <hip/hip_bf16.h>
#include <cmath>

#define B_    2
#define T_    1024
#define BT_   2048
#define C_    1024
#define H_    16
#define NH_   4096
#define E_    2
#define WIN_  256
#define G_    8          // attention hb-chunk size

typedef unsigned short u16;
typedef __attribute__((ext_vector_type(8))) short short8;
typedef __attribute__((ext_vector_type(4))) float f32x4;

__device__ __forceinline__ u16 f2b(float f) {
    __hip_bfloat16 h = __float2bfloat16(f);
    return *(u16*)&h;
}
__device__ __forceinline__ float b2f(u16 u) {
    __hip_bfloat16 h; *(u16*)&h = u;
    return __bfloat162float(h);
}

// async global->LDS, 16B per lane; lds base must be wave-uniform (HW adds lane*16)
__device__ __forceinline__ void gl_lds16(const u16* g, u16* l) {
    __builtin_amdgcn_global_load_lds(
        (const __attribute__((address_space(1))) unsigned int*)g,
        (__attribute__((address_space(3))) unsigned int*)l, 16, 0, 0);
}

// ============================================================================
// MFMA GEMM, TN path: A bf16 [M][K] (lda), B bf16 [N][K] (ldb).
// TILE: 128 x (TNJ*32), BK=32. 4 waves in 2x2. Batched via z with offset coefs.
// Staging: global_load_lds w16, linear LDS, XOR slot-swizzle on SOURCE+READ.
// Double-buffered: STAGE(next) issued before COMPUTE(cur); 1 barrier/K-step.
// Requires K/32 even (all call sites satisfy).
// EPI: 0=f32, 1=bf16, 2=scores(scale+window-mask,f32), 3=x1(bias+res,f32),
//      4=bf16+bias, 5=f32 res+coef*(v+bias), 6=f32 +=coef*(v+bias)
// WINK: 1 = skip K-prefix below attention window (PV GEMM; exact-zero weights)
// ============================================================================
template<int TNJ, int EPI, int WINK = 0>
__global__ __launch_bounds__(256) void gemm_tn(
    const u16* __restrict__ A, const u16* __restrict__ B,
    float* __restrict__ Cf, u16* __restrict__ Cb,
    const float* __restrict__ bias, const float* __restrict__ res,
    const float* __restrict__ coef,
    int K, int lda, int ldb, int ldc,
    int hb0, long aCz, long aCb, long aCh,
    long bCb, long bCh, long cCz, long cCb, long cCh)
{
    constexpr int TN = TNJ * 32;
    constexpr int ABUF = 128 * 32;       // u16 units
    constexpr int BBUF = TN * 32;
    constexpr int BUFSZ = ABUF + BBUF;
    constexpr int NINST = 8 + TN / 16;   // 1KB staging instructions per K-step
    constexpr int NPW = NINST / 4;       // per wave
    __shared__ alignas(16) u16 L[2 * BUFSZ];
    int tid = threadIdx.x;
    int z = blockIdx.z;
    int hb = hb0 + z;
    int hh = hb >> 1, bb = hb & 1;
    const u16* Ap = A + aCz * z + aCb * bb + aCh * hh + (size_t)blockIdx.y * 128 * lda;
    const u16* Bp = B + bCb * bb + bCh * hh + (size_t)blockIdx.x * TN * ldb;
    size_t cOff = (size_t)(cCz * z + cCb * bb + cCh * hh);

    int lane = tid & 63, w = tid >> 6;
    int wr = (w >> 1) * 64, wc = (w & 1) * (TNJ * 16);
    int fm = lane & 15;

    int rBase = blockIdx.y * 128 + wr + (lane >> 4) * 4;
    int cBase = blockIdx.x * TN + wc + fm;

    // scores: fully-masked tile fast path (col <= row - WIN_ everywhere)
    if (EPI == 2) {
        if ((int)blockIdx.x * TN + TN - 1 <= (int)blockIdx.y * 128 - WIN_) {
            #pragma unroll
            for (int i = 0; i < 4; ++i)
                #pragma unroll
                for (int j = 0; j < TNJ; ++j)
                    #pragma unroll
                    for (int r = 0; r < 4; ++r)
                        Cf[cOff + (size_t)(rBase + i * 16 + r) * ldc + cBase + j * 16] = -INFINITY;
            return;
        }
    }

    // PV: softmax weights are exactly 0 for col s <= row - WIN_; skip K-prefix.
    int kBeg = 0;
    if (WINK) {
        int s = (int)blockIdx.y * 128 - (WIN_ - 1);
        kBeg = (s > 0) ? ((s >> 5) << 5) : 0;
    }

    // --- staging precompute: per-wave instructions, pre-swizzled global src ---
    const u16* gsrc[NPW];
    int loff[NPW];
    #pragma unroll
    for (int ii = 0; ii < NPW; ++ii) {
        int inst = w * NPW + ii;
        int lrow = lane >> 2;
        int sx = lane & 3;
        if (inst < 8) {
            int row = inst * 16 + lrow;
            gsrc[ii] = Ap + (size_t)row * lda + ((sx ^ ((row >> 1) & 3)) * 8);
            loff[ii] = inst * 512;
        } else {
            int row = (inst - 8) * 16 + lrow;
            gsrc[ii] = Bp + (size_t)row * ldb + ((sx ^ ((row >> 1) & 3)) * 8);
            loff[ii] = ABUF + (inst - 8) * 512;
        }
    }
    // --- fragment read offsets (u16 units), same XOR swizzle ---
    int aoff[4], boff[TNJ];
    #pragma unroll
    for (int i = 0; i < 4; ++i) {
        int r = wr + i * 16 + fm;
        aoff[i] = r * 32 + (((lane >> 4) ^ ((r >> 1) & 3)) * 8);
    }
    #pragma unroll
    for (int j = 0; j < TNJ; ++j) {
        int r = wc + j * 16 + fm;
        boff[j] = ABUF + r * 32 + (((lane >> 4) ^ ((r >> 1) & 3)) * 8);
    }

    f32x4 acc[4][TNJ];
    #pragma unroll
    for (int i = 0; i < 4; ++i)
        #pragma unroll
        for (int j = 0; j < TNJ; ++j)
            acc[i][j] = (f32x4){0.f, 0.f, 0.f, 0.f};

    auto STAGE = [&](int bufOff, int kk) {
        #pragma unroll
        for (int ii = 0; ii < NPW; ++ii)
            gl_lds16(gsrc[ii] + kk, L + bufOff + loff[ii]);
    };
    auto COMPUTE = [&](int bufOff) {
        short8 af[4], bf[TNJ];
        #pragma unroll
        for (int i = 0; i < 4; ++i) af[i] = *(const short8*)(L + bufOff + aoff[i]);
        #pragma unroll
        for (int j = 0; j < TNJ; ++j) bf[j] = *(const short8*)(L + bufOff + boff[j]);
        #pragma unroll
        for (int i = 0; i < 4; ++i)
            #pragma unroll
            for (int j = 0; j < TNJ; ++j)
                acc[i][j] = __builtin_amdgcn_mfma_f32_16x16x32_bf16(af[i], bf[j], acc[i][j], 0, 0, 0);
    };

    int nt = (K - kBeg) >> 5;            // even at all call sites
    STAGE(0, kBeg);
    __syncthreads();
    for (int t = 0; t < nt; t += 2) {
        STAGE(BUFSZ, kBeg + (t + 1) * 32);
        COMPUTE(0);
        __syncthreads();
        if (t + 2 < nt) STAGE(0, kBeg + (t + 2) * 32);
        COMPUTE(BUFSZ);
        __syncthreads();
    }

    #pragma unroll
    for (int i = 0; i < 4; ++i)
        #pragma unroll
        for (int j = 0; j < TNJ; ++j)
            #pragma unroll
            for (int r = 0; r < 4; ++r) {
                int row = rBase + i * 16 + r;
                int col = cBase + j * 16;
                float v = acc[i][j][r];
                size_t o = cOff + (size_t)row * ldc + col;
                if (EPI == 0) Cf[o] = v;
                else if (EPI == 1) Cb[o] = f2b(v);
                else if (EPI == 2) {
                    v *= 0.125f;
                    if (col <= row - WIN_) v = -INFINITY;  // past-window mask only
                    Cf[o] = v;
                } else if (EPI == 3) {  // X1: + bias + residual
                    Cf[o] = v + bias[col] + res[(size_t)row * ldc + col];
                } else if (EPI == 4) {  // bf16 + bias (MoE h1)
                    Cb[o] = f2b(v + bias[col]);
                } else if (EPI == 5) {  // MoE out, first expert
                    Cf[o] = res[o] + coef[row] * (v + bias[col]);
                } else {                // MoE out, accumulate
                    Cf[o] += coef[row] * (v + bias[col]);
                }
            }
}

// ============================================================================
// Dual TN GEMM: p = swish(A@B1^T + bs; beta) * (A@B2^T + bg), bf16 out.
// A bf16 [M][K]; B1,B2 bf16 [N][K]. TILE 128x64 (x2 B). Same dbuf scheme.
// ============================================================================
__global__ __launch_bounds__(256) void gemm_tn_dual(
    const u16* __restrict__ A, const u16* __restrict__ B1,
    const u16* __restrict__ B2, const float* __restrict__ bs,
    const float* __restrict__ bg, const float* __restrict__ betaP,
    u16* __restrict__ P, int K, int lda, int ldb, int ldc)
{
    constexpr int ABUF = 128 * 32;
    constexpr int BBUF = 64 * 32;
    constexpr int BUFSZ = ABUF + 2 * BBUF;   // 8192 u16 = 16KB
    __shared__ alignas(16) u16 L[2 * BUFSZ];
    int tid = threadIdx.x;
    const u16* Ap  = A  + (size_t)blockIdx.y * 128 * lda;
    const u16* B1p = B1 + (size_t)blockIdx.x * 64 * ldb;
    const u16* B2p = B2 + (size_t)blockIdx.x * 64 * ldb;

    int lane = tid & 63, w = tid >> 6;
    int wr = (w >> 1) * 64, wc = (w & 1) * 32;
    int fm = lane & 15;

    // 16 instructions: 0-7 A, 8-11 B1, 12-15 B2 -> 4 per wave
    const u16* gsrc[4];
    int loff[4];
    #pragma unroll
    for (int ii = 0; ii < 4; ++ii) {
        int inst = w * 4 + ii;
        int lrow = lane >> 2;
        int sx = lane & 3;
        if (inst < 8) {
            int row = inst * 16 + lrow;
            gsrc[ii] = Ap + (size_t)row * lda + ((sx ^ ((row >> 1) & 3)) * 8);
            loff[ii] = inst * 512;
        } else if (inst < 12) {
            int row = (inst - 8) * 16 + lrow;
            gsrc[ii] = B1p + (size_t)row * ldb + ((sx ^ ((row >> 1) & 3)) * 8);
            loff[ii] = ABUF + (inst - 8) * 512;
        } else {
            int row = (inst - 12) * 16 + lrow;
            gsrc[ii] = B2p + (size_t)row * ldb + ((sx ^ ((row >> 1) & 3)) * 8);
            loff[ii] = ABUF + BBUF + (inst - 12) * 512;
        }
    }
    int aoff[4], boff[2];
    #pragma unroll
    for (int i = 0; i < 4; ++i) {
        int r = wr + i * 16 + fm;
        aoff[i] = r * 32 + (((lane >> 4) ^ ((r >> 1) & 3)) * 8);
    }
    #pragma unroll
    for (int j = 0; j < 2; ++j) {
        int r = wc + j * 16 + fm;
        boff[j] = ABUF + r * 32 + (((lane >> 4) ^ ((r >> 1) & 3)) * 8);
    }

    f32x4 a1[4][2], a2[4][2];
    #pragma unroll
    for (int i = 0; i < 4; ++i)
        #pragma unroll
        for (int j = 0; j < 2; ++j) {
            a1[i][j] = (f32x4){0.f, 0.f, 0.f, 0.f};
            a2[i][j] = (f32x4){0.f, 0.f, 0.f, 0.f};
        }

    auto STAGE = [&](int bufOff, int kk) {
        #pragma unroll
        for (int ii = 0; ii < 4; ++ii)
            gl_lds16(gsrc[ii] + kk, L + bufOff + loff[ii]);
    };
    auto COMPUTE = [&](int bufOff) {
        short8 af[4], b1f[2], b2f[2];
        #pragma unroll
        for (int i = 0; i < 4; ++i) af[i] = *(const short8*)(L + bufOff + aoff[i]);
        #pragma unroll
        for (int j = 0; j < 2; ++j) {
            b1f[j] = *(const short8*)(L + bufOff + boff[j]);
            b2f[j] = *(const short8*)(L + bufOff + BBUF + boff[j]);
        }
        #pragma unroll
        for (int i = 0; i < 4; ++i)
            #pragma unroll
            for (int j = 0; j < 2; ++j) {
                a1[i][j] = __builtin_amdgcn_mfma_f32_16x16x32_bf16(af[i], b1f[j], a1[i][j], 0, 0, 0);
                a2[i][j] = __builtin_amdgcn_mfma_f32_16x16x32_bf16(af[i], b2f[j], a2[i][j], 0, 0, 0);
            }
    };

    int nt = K >> 5;
    STAGE(0, 0);
    __syncthreads();
    for (int t = 0; t < nt; t += 2) {
        STAGE(BUFSZ, (t + 1) * 32);
        COMPUTE(0);
        __syncthreads();
        if (t + 2 < nt) STAGE(0, (t + 2) * 32);
        COMPUTE(BUFSZ);
        __syncthreads();
    }

    float beta = betaP[0];
    int rBase = blockIdx.y * 128 + wr + (lane >> 4) * 4;
    int cBase = blockIdx.x * 64 + wc + fm;
    #pragma unroll
    for (int i = 0; i < 4; ++i)
        #pragma unroll
        for (int j = 0; j < 2; ++j)
            #pragma unroll
            for (int r = 0; r < 4; ++r) {
                int row = rBase + i * 16 + r;
                int col = cBase + j * 16;
                float sx = a1[i][j][r] + bs[col];
                float gl = a2[i][j][r] + bg[col];
                float sw = sx / (1.f + expf(-beta * sx));
                P[(size_t)row * ldc + col] = f2b(sw * gl);
            }
}

// ============================================================================
// Weight transpose: f32 [K][N] -> bf16 [N][K], LDS-tiled 64x64.
// ============================================================================
__global__ __launch_bounds__(256) void transpose_w(
    const float* __restrict__ W, u16* __restrict__ out, int K, int N)
{
    __shared__ u16 Ls[64][66];
    int n0 = blockIdx.x * 64, k0 = blockIdx.y * 64;
    int tid = threadIdx.x;
    #pragma unroll
    for (int i = 0; i < 16; ++i) {
        int idx = tid + i * 256;
        int r = idx >> 6, c = idx & 63;           // r=k-local, c=n-local
        Ls[r][c] = f2b(W[(size_t)(k0 + r) * N + n0 + c]);
    }
    __syncthreads();
    #pragma unroll
    for (int i = 0; i < 16; ++i) {
        int idx = tid + i * 256;
        int n = idx >> 6, k = idx & 63;
        out[(size_t)(n0 + n) * K + k0 + k] = Ls[k][n];
    }
}

// ============================================================================
// Small kernels
// ============================================================================
// LayerNorm (ddof=1): out bf16 always; optional f32 copy.
__global__ __launch_bounds__(256) void ln_kernel(
    const float* __restrict__ x, const float* __restrict__ g,
    const float* __restrict__ b, u16* __restrict__ outB,
    float* __restrict__ outF, int wantF)
{
    int row = blockIdx.x;
    int tid = threadIdx.x;
    __shared__ float rs[256], rq[256];
    const float* xp = x + (size_t)row * C_;
    float s = 0.f, q = 0.f;
    for (int c = tid; c < C_; c += 256) {
        float v = xp[c];
        s += v; q += v * v;
    }
    rs[tid] = s; rq[tid] = q; __syncthreads();
    for (int off = 128; off > 0; off >>= 1) {
        if (tid < off) { rs[tid] += rs[tid + off]; rq[tid] += rq[tid + off]; }
        __syncthreads();
    }
    float mean = rs[0] * (1.f / C_);
    float var  = (rq[0] - (float)C_ * mean * mean) * (1.f / (C_ - 1));
    float inv  = rsqrtf(var + 1e-5f);
    for (int c = tid; c < C_; c += 256) {
        float v = (xp[c] - mean) * inv * g[c] + b[c];
        outB[(size_t)row * C_ + c] = f2b(v);
        if (wantF) outF[(size_t)row * C_ + c] = v;
    }
}

// Wk/Wv: f32 [H][C][D] -> bf16 [hd][c]
__global__ __launch_bounds__(256) void prep_whcd(const float* __restrict__ W, u16* __restrict__ out) {
    int idx = blockIdx.x * 256 + threadIdx.x;
    int hd = idx >> 10, c = idx & 1023;
    out[idx] = f2b(W[((size_t)(hd >> 6) * C_ + c) * 64 + (hd & 63)]);
}
// Wq summed over q: f32 [H][2][C][D] -> bf16 [hd][c]
__global__ __launch_bounds__(256) void prep_wq(const float* __restrict__ W, u16* __restrict__ out) {
    int idx = blockIdx.x * 256 + threadIdx.x;
    int hd = idx >> 10, c = idx & 1023;
    int h = hd >> 6, d = hd & 63;
    size_t i0 = (((size_t)h * 2 + 0) * C_ + c) * 64 + d;
    size_t i1 = (((size_t)h * 2 + 1) * C_ + c) * 64 + d;
    out[idx] = f2b(W[i0] + W[i1]);
}
// Wp: f32 [K][N] -> bf16 [N][K]
__global__ __launch_bounds__(256) void prep_wp(const float* __restrict__ W, u16* __restrict__ out) {
    int idx = blockIdx.x * 256 + threadIdx.x;
    int n = idx >> 10, k = idx & 1023;
    out[idx] = f2b(W[(size_t)k * C_ + n]);
}
// KrT[hb][s][d] = Kbf[(b*1024 + d*16 + (s>>6))*1024 + h*64 + (s&63)]
__global__ __launch_bounds__(256) void prep_krt(const u16* __restrict__ Kbf, u16* __restrict__ out) {
    int idx = blockIdx.x * 256 + threadIdx.x;
    int hb = idx >> 16, rem = idx & 65535;
    int s = rem >> 6, d = rem & 63;
    int h = hb >> 1, b = hb & 1;
    out[idx] = Kbf[((size_t)(b * 1024 + d * 16 + (s >> 6))) * 1024 + h * 64 + (s & 63)];
}
// VT[hb][d][s] = Vbf[(b*1024+s)*1024 + h*64 + d]
__global__ __launch_bounds__(256) void prep_vt(const u16* __restrict__ Vbf, u16* __restrict__ out) {
    int idx = blockIdx.x * 256 + threadIdx.x;
    int hb = idx >> 16, rem = idx & 65535;
    int d = rem >> 10, s = rem & 1023;
    int h = hb >> 1, b = hb & 1;
    out[idx] = Vbf[((size_t)(b * 1024 + s)) * 1024 + h * 64 + d];
}

// Row softmax over 1024 f32, in-place write as bf16 into row start.
__global__ __launch_bounds__(256) void softmax_rows(float* __restrict__ sc) {
    float* rp = sc + (size_t)blockIdx.x * 1024;
    int tid = threadIdx.x;
    float4 v = *(float4*)(rp + tid * 4);
    __shared__ float red[256];
    float mx = fmaxf(fmaxf(v.x, v.y), fmaxf(v.z, v.w));
    red[tid] = mx; __syncthreads();
    for (int off = 128; off > 0; off >>= 1) {
        if (tid < off) red[tid] = fmaxf(red[tid], red[tid + off]);
        __syncthreads();
    }
    mx = red[0]; __syncthreads();
    float e0 = expf(v.x - mx), e1 = expf(v.y - mx), e2 = expf(v.z - mx), e3 = expf(v.w - mx);
    red[tid] = e0 + e1 + e2 + e3; __syncthreads();
    for (int off = 128; off > 0; off >>= 1) {
        if (tid < off) red[tid] += red[tid + off];
        __syncthreads();
    }
    float inv = 1.f / red[0];
    u16* wp = (u16*)rp;
    wp[tid * 4 + 0] = f2b(e0 * inv);
    wp[tid * 4 + 1] = f2b(e1 * inv);
    wp[tid * 4 + 2] = f2b(e2 * inv);
    wp[tid * 4 + 3] = f2b(e3 * inv);
}

// Router: logits from f32 xn2, max + argmax per token.
__global__ __launch_bounds__(256) void router_kernel(
    const float* __restrict__ xn2, const float* __restrict__ Wg,
    const float* __restrict__ bgp, float* __restrict__ mOut, int* __restrict__ topiOut)
{
    int g = blockIdx.x;
    int tid = threadIdx.x;
    __shared__ float r0[256], r1[256];
    const float* xp = xn2 + (size_t)g * C_;
    float a0 = 0.f, a1 = 0.f;
    for (int c = tid; c < C_; c += 256) {
        float xv = xp[c];
        a0 += xv * Wg[c * 2 + 0];
        a1 += xv * Wg[c * 2 + 1];
    }
    r0[tid] = a0; r1[tid] = a1; __syncthreads();
    for (int off = 128; off > 0; off >>= 1) {
        if (tid < off) { r0[tid] += r0[tid + off]; r1[tid] += r1[tid + off]; }
        __syncthreads();
    }
    if (tid == 0) {
        float l0 = r0[0] + bgp[0];
        float l1 = r1[0] + bgp[1];
        topiOut[g] = (l1 > l0) ? 1 : 0;
        mOut[g] = fmaxf(l0, l1);
    }
}

// Softmax of max-logit over TOKEN axis (faithful bug) -> per-expert coef.
__global__ __launch_bounds__(256) void gatecoef_kernel(
    const float* __restrict__ m, const int* __restrict__ topi, float* __restrict__ coef)
{
    int b = blockIdx.x;
    int tid = threadIdx.x;
    __shared__ float red[256];
    const float* mp = m + (size_t)b * T_;
    float mx = -INFINITY;
    for (int t = tid; t < T_; t += 256) mx = fmaxf(mx, mp[t]);
    red[tid] = mx; __syncthreads();
    for (int off = 128; off > 0; off >>= 1) {
        if (tid < off) red[tid] = fmaxf(red[tid], red[tid + off]);
        __syncthreads();
    }
    mx = red[0]; __syncthreads();
    float s = 0.f;
    for (int t = tid; t < T_; t += 256) s += expf(mp[t] - mx);
    red[tid] = s; __syncthreads();
    for (int off = 128; off > 0; off >>= 1) {
        if (tid < off) red[tid] += red[tid + off];
        __syncthreads();
    }
    float inv = 1.f / red[0];
    for (int t = tid; t < T_; t += 256) {
        int g = b * T_ + t;
        float wv = expf(mp[t] - mx) * inv;
        int e = topi[g];
        coef[g]       = (e == 0) ? wv : 0.f;
        coef[BT_ + g] = (e == 1) ? wv : 0.f;
    }
}

// ============================================================================
// Host
// ============================================================================
extern "C" void kernel_launch(void* const* d_in, const int* in_sizes, int n_in,
                              void* d_out, int out_size, void* d_ws, size_t ws_size,
                              hipStream_t stream)
{
    const float* x    = (const float*)d_in[0];
    const float* Wq   = (const float*)d_in[1];
    const float* Wk   = (const float*)d_in[2];
    const float* Wv   = (const float*)d_in[3];
    const float* Wp   = (const float*)d_in[4];
    const float* bp   = (const float*)d_in[5];
    const float* ln1g = (const float*)d_in[6];
    const float* ln1b = (const float*)d_in[7];
    const float* ln2g = (const float*)d_in[8];
    const float* ln2b = (const float*)d_in[9];
    const float* Wg   = (const float*)d_in[10];
    const float* bg   = (const float*)d_in[11];
    const float* Ew1  = (const float*)d_in[12];
    const float* Eb1  = (const float*)d_in[13];
    const float* Ews  = (const float*)d_in[14];
    const float* Ebs  = (const float*)d_in[15];
    const float* Ebeta= (const float*)d_in[16];
    const float* Ewg  = (const float*)d_in[17];
    const float* Ebg  = (const float*)d_in[18];
    const float* Ew2  = (const float*)d_in[19];
    const float* Eb2  = (const float*)d_in[20];
    float* out = (float*)d_out;

    char* ws = (char*)d_ws;
    const size_t MB = 1024 * 1024;
    // Phase-A layout (offsets in bytes); phase-B aliases dead regions.
    u16*  xnbf   = (u16*) (ws + 0);        // 4 MB   (later: xn2bf)
    u16*  WqsT   = (u16*) (ws + 4*MB);     // 2 MB   (phase-B: W1T/W2T)
    u16*  WkT    = (u16*) (ws + 6*MB);     // 2 MB
    u16*  WvT    = (u16*) (ws + 8*MB);     // 2 MB
    u16*  WpT    = (u16*) (ws + 10*MB);    // 2 MB
    u16*  Qbf    = (u16*) (ws + 12*MB);    // 4 MB   (MoE: p 12-28)
    u16*  Kbf    = (u16*) (ws + 16*MB);    // 4 MB
    u16*  Vbf    = (u16*) (ws + 20*MB);    // 4 MB
    u16*  KrT    = (u16*) (ws + 24*MB);    // 4 MB
    u16*  VT     = (u16*) (ws + 28*MB);    // 4 MB   (later: xn2f 28-36)
    u16*  Obf    = (u16*) (ws + 32*MB);    // 4 MB
    float* x1    = (float*)(ws + 36*MB);   // 8 MB
    float* sc    = (float*)(ws + 44*MB);   // 32 MB scores chunk G=8 (MoE: h1 44-60; mbuf region 61 temporally disjoint)
    float* mbuf  = (float*)(ws + 61*MB);   // 8 KB  (written step 7, after sc dead)
    int*   topi  = (int*)  (ws + 61*MB + 16*1024);
    float* coef  = (float*)(ws + 61*MB + 32*1024);  // [2][2048]
    // Phase-B aliases
    u16*  xn2bf  = (u16*) (ws + 0);
    float* xn2f  = (float*)(ws + 28*MB);
    u16*  h1     = (u16*) (ws + 44*MB);    // 16 MB [2048][4096]
    u16*  pbuf   = (u16*) (ws + 12*MB);    // 16 MB [2048][4096]
    // Phase-B bf16 transposed expert weights
    u16*  W1T    = (u16*) (ws + 4*MB);     // 8 MB [4096][1024] (dead prep region)
    u16*  W2T    = (u16*) (ws + 4*MB);     // 8 MB [1024][4096] (sequenced after W1T)
    u16*  WsT    = (u16*) (ws + 62*MB);    // 32 MB [4096][4096]
    u16*  WgT    = (u16*) (ws + 94*MB);    // 32 MB [4096][4096]  -> peak ws = 126 MB

    // --- 1. LN1 -> bf16 ---
    ln_kernel<<<BT_, 256, 0, stream>>>(x, ln1g, ln1b, xnbf, nullptr, 0);

    // --- 2. weight prep ---
    prep_whcd<<<C_*C_/256, 256, 0, stream>>>(Wk, WkT);
    prep_whcd<<<C_*C_/256, 256, 0, stream>>>(Wv, WvT);
    prep_wq  <<<C_*C_/256, 256, 0, stream>>>(Wq, WqsT);
    prep_wp  <<<C_*C_/256, 256, 0, stream>>>(Wp, WpT);

    // --- 3. Q/K/V projections (TN, bf16 out) ---
    {
        dim3 grid(16, 16, 1);
        gemm_tn<2,1><<<grid, 256, 0, stream>>>(xnbf, WqsT, nullptr, Qbf, nullptr, nullptr, nullptr,
            C_, C_, C_, C_, 0, 0,0,0, 0,0, 0,0,0);
        gemm_tn<2,1><<<grid, 256, 0, stream>>>(xnbf, WkT, nullptr, Kbf, nullptr, nullptr, nullptr,
            C_, C_, C_, C_, 0, 0,0,0, 0,0, 0,0,0);
        gemm_tn<2,1><<<grid, 256, 0, stream>>>(xnbf, WvT, nullptr, Vbf, nullptr, nullptr, nullptr,
            C_, C_, C_, C_, 0, 0,0,0, 0,0, 0,0,0);
    }
    prep_krt<<<H_*B_*T_*64/256, 256, 0, stream>>>(Kbf, KrT);
    prep_vt <<<H_*B_*T_*64/256, 256, 0, stream>>>(Vbf, VT);

    // --- 4. attention in hb-chunks of G_ ---
    for (int chunk = 0; chunk < (H_*B_)/G_; ++chunk) {
        int hb0 = chunk * G_;
        // scores = Q·KrT^T * 0.125, window mask; f32 [G][1024][1024]
        gemm_tn<4,2><<<dim3(8, 8, G_), 256, 0, stream>>>(
            Qbf, KrT, sc, nullptr, nullptr, nullptr, nullptr,
            64, C_, 64, 1024, hb0,
            /*aCz*/0, /*aCb*/1048576, /*aCh*/64,
            /*bCb*/65536, /*bCh*/131072,
            /*cCz*/1048576, 0, 0);
        // softmax rows, in-place -> bf16
        softmax_rows<<<G_*1024, 256, 0, stream>>>(sc);
        // O = W·VT^T -> Obf[b*T+t][h*64+d]; WINK skips exact-zero K-prefix
        gemm_tn<2,1,1><<<dim3(1, 8, G_), 256, 0, stream>>>(
            (u16*)sc, VT, nullptr, Obf, nullptr, nullptr, nullptr,
            1024, 2048, 1024, 1024, hb0,
            /*aCz*/2097152, 0, 0,
            /*bCb*/65536, /*bCh*/131072,
            /*cCz*/0, /*cCb*/1048576, /*cCh*/64);
    }

    // --- 5. x1 = x + Obf@WpT + bp ---
    gemm_tn<2,3><<<dim3(16, 16, 1), 256, 0, stream>>>(
        Obf, WpT, x1, nullptr, bp, x, nullptr,
        C_, C_, C_, C_, 0, 0,0,0, 0,0, 0,0,0);

    // --- 6. LN2 (f32 for router + bf16 for GEMMs) ---
    ln_kernel<<<BT_, 256, 0, stream>>>(x1, ln2g, ln2b, xn2bf, xn2f, 1);

    // --- 7. router + gate ---
    router_kernel<<<BT_, 256, 0, stream>>>(xn2f, Wg, bg, mbuf, topi);
    gatecoef_kernel<<<B_, 256, 0, stream>>>(mbuf, topi, coef);

    // --- 8. MoE: pre-transposed bf16 weights, all GEMMs on TN path ---
    for (int e = 0; e < E_; ++e) {
        // W1T = Ew1[e]^T bf16 [4096][1024]
        transpose_w<<<dim3(NH_/64, C_/64), 256, 0, stream>>>(
            Ew1 + (size_t)e * C_ * NH_, W1T, C_, NH_);
        // h1 = xn2@Ew1[e] + Eb1[e] -> bf16 [2048][4096]
        gemm_tn<4,4><<<dim3(NH_/128, 16), 256, 0, stream>>>(
            xn2bf, W1T, nullptr, h1, Eb1 + (size_t)e * NH_, nullptr, nullptr,
            C_, C_, C_, NH_, 0, 0,0,0, 0,0, 0,0,0);
        // WsT/WgT = Ews[e]^T / Ewg[e]^T bf16 [4096][4096]
        transpose_w<<<dim3(NH_/64, NH_/64), 256, 0, stream>>>(
            Ews + (size_t)e * NH_ * NH_, WsT, NH_, NH_);
        transpose_w<<<dim3(NH_/64, NH_/64), 256, 0, stream>>>(
            Ewg + (size_t)e * NH_ * NH_, WgT, NH_, NH_);
        // p = swish(h1@Ews+Ebs) * (h1@Ewg+Ebg) -> bf16
        gemm_tn_dual<<<dim3(NH_/64, 16), 256, 0, stream>>>(
            h1, WsT, WgT, Ebs + (size_t)e * NH_, Ebg + (size_t)e * NH_, Ebeta + e,
            pbuf, NH_, NH_, NH_, NH_);
        // W2T = Ew2[e]^T bf16 [1024][4096]
        transpose_w<<<dim3(C_/64, NH_/64), 256, 0, stream>>>(
            Ew2 + (size_t)e * NH_ * C_, W2T, NH_, C_);
        // out (+)= coef_e * (p@Ew2[e] + Eb2[e])  (+ x1 on first pass)
        if (e == 0)
            gemm_tn<2,5><<<dim3(C_/64, 16), 256, 0, stream>>>(
                pbuf, W2T, out, nullptr, Eb2, x1, coef + 0 * BT_,
                NH_, NH_, NH_, C_, 0, 0,0,0, 0,0, 0,0,0);
        else
            gemm_tn<2,6><<<dim3(C_/64, 16), 256, 0, stream>>>(
                pbuf, W2T, out, nullptr, Eb2 + (size_t)e * C_, nullptr, coef + (size_t)e * BT_,
                NH_, NH_, NH_, C_, 0, 0,0,0, 0,0, 0,0,0);
    }
}

// Round 4
// 1041.833 us; speedup vs baseline: 1.5884x; 1.1387x over previous
//
#include <hip/hip_runtime.h>
#include <hip/hip_bf16.h>
#include <cmath>

#define B_    2
#define T_    1024
#define BT_   2048
#define C_    1024
#define H_    16
#define NH_   4096
#define E_    2
#define WIN_  256
#define G_    8          // attention hb-chunk size

typedef unsigned short u16;
typedef __attribute__((ext_vector_type(8))) short short8;
typedef __attribute__((ext_vector_type(4))) float f32x4;

__device__ __forceinline__ u16 f2b(float f) {
    __hip_bfloat16 h = __float2bfloat16(f);
    return *(u16*)&h;
}

// async global->LDS, 16B per lane; lds base must be wave-uniform (HW adds lane*16)
__device__ __forceinline__ void gl_lds16(const u16* g, u16* l) {
    __builtin_amdgcn_global_load_lds(
        (const __attribute__((address_space(1))) unsigned int*)g,
        (__attribute__((address_space(3))) unsigned int*)l, 16, 0, 0);
}

// counted vmcnt wait; "memory" clobber pins ordering vs loads/ds ops
template<int N> __device__ __forceinline__ void waitvm() {
    asm volatile("s_waitcnt vmcnt(%0)" :: "n"(N) : "memory");
}
// raw barrier fenced by sched_barrier so LDS reads/writes can't cross it
__device__ __forceinline__ void barrier_raw() {
    __builtin_amdgcn_sched_barrier(0);
    __builtin_amdgcn_s_barrier();
    __builtin_amdgcn_sched_barrier(0);
}

// XCD-chunked bijective swizzle (grids with x*y % 8 == 0): each XCD gets a
// contiguous bx-range -> B-panel slice stays in its L2.
__device__ __forceinline__ void xcd_swizzle(int& bx, int& by) {
    int gx = gridDim.x, gy = gridDim.y;
    int tot = gx * gy;
    if ((tot & 7) == 0) {
        int flat = by * gx + bx;
        int q = tot >> 3;
        int lg = (flat & 7) * q + (flat >> 3);
        bx = lg / gy; by = lg % gy;
    }
}

// ============================================================================
// MFMA GEMM, TN path: A bf16 [M][K] (lda), B bf16 [N][K] (ldb).
// TILE: 128 x (TNJ*32), BK=32. 4 waves 2x2. Batched via z with offset coefs.
// Staging: global_load_lds w16, linear LDS, XOR slot-swizzle on SOURCE+READ.
// PIPE=1: depth-4 ring, stage-3-ahead, counted vmcnt (never 0 in loop),
//         raw barriers. Requires nt multiple of 4, nt>=4.
// PIPE=0: simple dbuf with __syncthreads (nt even).
// EPI: 0=f32, 1=bf16, 2=scores(scale+window-mask,f32), 3=x1(bias+res,f32),
//      4=bf16+bias, 5=f32 res+coef*(v+bias), 6=f32 +=coef*(v+bias)
// WINK: 1 = skip K-prefix below attention window (PV GEMM; exact-zero weights)
// ============================================================================
template<int TNJ, int EPI, int WINK, int PIPE>
__global__ __launch_bounds__(256) void gemm_tn(
    const u16* __restrict__ A, const u16* __restrict__ B,
    float* __restrict__ Cf, u16* __restrict__ Cb,
    const float* __restrict__ bias, const float* __restrict__ res,
    const float* __restrict__ coef,
    int K, int lda, int ldb, int ldc,
    int hb0, long aCz, long aCb, long aCh,
    long bCb, long bCh, long cCz, long cCb, long cCh)
{
    constexpr int TN = TNJ * 32;
    constexpr int ABUF = 128 * 32;       // u16 units
    constexpr int BBUF = TN * 32;
    constexpr int BUFSZ = ABUF + BBUF;
    constexpr int NDEEP = PIPE ? 4 : 2;
    constexpr int NINST = 8 + TN / 16;   // 1KB staging instructions per K-step
    constexpr int NPW = NINST / 4;       // per wave
    __shared__ alignas(16) u16 L[NDEEP * BUFSZ];
    int tid = threadIdx.x;
    int bx = blockIdx.x, by = blockIdx.y;
    xcd_swizzle(bx, by);
    int z = blockIdx.z;
    int hb = hb0 + z;
    int hh = hb >> 1, bb = hb & 1;
    const u16* Ap = A + aCz * z + aCb * bb + aCh * hh + (size_t)by * 128 * lda;
    const u16* Bp = B + bCb * bb + bCh * hh + (size_t)bx * TN * ldb;
    size_t cOff = (size_t)(cCz * z + cCb * bb + cCh * hh);

    int lane = tid & 63, w = tid >> 6;
    int wr = (w >> 1) * 64, wc = (w & 1) * (TNJ * 16);
    int fm = lane & 15;

    int rBase = by * 128 + wr + (lane >> 4) * 4;
    int cBase = bx * TN + wc + fm;

    // scores: fully-masked tile fast path (col <= row - WIN_ everywhere)
    if (EPI == 2) {
        if (bx * TN + TN - 1 <= by * 128 - WIN_) {
            #pragma unroll
            for (int i = 0; i < 4; ++i)
                #pragma unroll
                for (int j = 0; j < TNJ; ++j)
                    #pragma unroll
                    for (int r = 0; r < 4; ++r)
                        Cf[cOff + (size_t)(rBase + i * 16 + r) * ldc + cBase + j * 16] = -INFINITY;
            return;
        }
    }

    // PV: softmax weights are exactly 0 for col s <= row - WIN_; skip K-prefix.
    int kBeg = 0;
    if (WINK) {
        int s = by * 128 - (WIN_ - 1);
        kBeg = (s > 0) ? ((s >> 5) << 5) : 0;
    }

    // --- staging precompute: per-wave instructions, pre-swizzled global src ---
    const u16* gsrc[NPW];
    int loff[NPW];
    #pragma unroll
    for (int ii = 0; ii < NPW; ++ii) {
        int inst = w * NPW + ii;
        int lrow = lane >> 2;
        int sx = lane & 3;
        if (inst < 8) {
            int row = inst * 16 + lrow;
            gsrc[ii] = Ap + (size_t)row * lda + ((sx ^ ((row >> 1) & 3)) * 8);
            loff[ii] = inst * 512;
        } else {
            int row = (inst - 8) * 16 + lrow;
            gsrc[ii] = Bp + (size_t)row * ldb + ((sx ^ ((row >> 1) & 3)) * 8);
            loff[ii] = ABUF + (inst - 8) * 512;
        }
    }
    // --- fragment read offsets (u16 units), same XOR swizzle ---
    int aoff[4], boff[TNJ];
    #pragma unroll
    for (int i = 0; i < 4; ++i) {
        int r = wr + i * 16 + fm;
        aoff[i] = r * 32 + (((lane >> 4) ^ ((r >> 1) & 3)) * 8);
    }
    #pragma unroll
    for (int j = 0; j < TNJ; ++j) {
        int r = wc + j * 16 + fm;
        boff[j] = ABUF + r * 32 + (((lane >> 4) ^ ((r >> 1) & 3)) * 8);
    }

    f32x4 acc[4][TNJ];
    #pragma unroll
    for (int i = 0; i < 4; ++i)
        #pragma unroll
        for (int j = 0; j < TNJ; ++j)
            acc[i][j] = (f32x4){0.f, 0.f, 0.f, 0.f};

    auto STAGE = [&](int bufOff, int kk) {
        #pragma unroll
        for (int ii = 0; ii < NPW; ++ii)
            gl_lds16(gsrc[ii] + kk, L + bufOff + loff[ii]);
    };
    auto COMPUTE = [&](int bufOff) {
        short8 af[4], bf[TNJ];
        #pragma unroll
        for (int i = 0; i < 4; ++i) af[i] = *(const short8*)(L + bufOff + aoff[i]);
        #pragma unroll
        for (int j = 0; j < TNJ; ++j) bf[j] = *(const short8*)(L + bufOff + boff[j]);
        __builtin_amdgcn_s_setprio(1);
        #pragma unroll
        for (int i = 0; i < 4; ++i)
            #pragma unroll
            for (int j = 0; j < TNJ; ++j)
                acc[i][j] = __builtin_amdgcn_mfma_f32_16x16x32_bf16(af[i], bf[j], acc[i][j], 0, 0, 0);
        __builtin_amdgcn_s_setprio(0);
    };

    int nt = (K - kBeg) >> 5;

    if (PIPE) {
        // prologue: fill 3 buffers
        STAGE(0 * BUFSZ, kBeg);
        STAGE(1 * BUFSZ, kBeg + 32);
        STAGE(2 * BUFSZ, kBeg + 64);
        auto PHASEF = [&](int bufC, int bufS, int kk) {
            STAGE(bufS, kk);
            waitvm<3 * NPW>();
            barrier_raw();
            COMPUTE(bufC);
            barrier_raw();
        };
        for (int p = 0; p < nt - 4; p += 4) {
            PHASEF(0 * BUFSZ, 3 * BUFSZ, kBeg + (p + 3) * 32);
            PHASEF(1 * BUFSZ, 0 * BUFSZ, kBeg + (p + 4) * 32);
            PHASEF(2 * BUFSZ, 1 * BUFSZ, kBeg + (p + 5) * 32);
            PHASEF(3 * BUFSZ, 2 * BUFSZ, kBeg + (p + 6) * 32);
        }
        // tail: 4 phases, descending counted waits
        STAGE(3 * BUFSZ, kBeg + (nt - 1) * 32);
        waitvm<3 * NPW>(); barrier_raw(); COMPUTE(0 * BUFSZ); barrier_raw();
        waitvm<2 * NPW>(); barrier_raw(); COMPUTE(1 * BUFSZ); barrier_raw();
        waitvm<1 * NPW>(); barrier_raw(); COMPUTE(2 * BUFSZ); barrier_raw();
        waitvm<0>();       barrier_raw(); COMPUTE(3 * BUFSZ);
    } else {
        STAGE(0, kBeg);
        __syncthreads();
        for (int t = 0; t < nt; t += 2) {
            STAGE(BUFSZ, kBeg + (t + 1) * 32);
            COMPUTE(0);
            __syncthreads();
            if (t + 2 < nt) STAGE(0, kBeg + (t + 2) * 32);
            COMPUTE(BUFSZ);
            __syncthreads();
        }
    }

    #pragma unroll
    for (int i = 0; i < 4; ++i)
        #pragma unroll
        for (int j = 0; j < TNJ; ++j)
            #pragma unroll
            for (int r = 0; r < 4; ++r) {
                int row = rBase + i * 16 + r;
                int col = cBase + j * 16;
                float v = acc[i][j][r];
                size_t o = cOff + (size_t)row * ldc + col;
                if (EPI == 0) Cf[o] = v;
                else if (EPI == 1) Cb[o] = f2b(v);
                else if (EPI == 2) {
                    v *= 0.125f;
                    if (col <= row - WIN_) v = -INFINITY;  // past-window mask only
                    Cf[o] = v;
                } else if (EPI == 3) {  // X1: + bias + residual
                    Cf[o] = v + bias[col] + res[(size_t)row * ldc + col];
                } else if (EPI == 4) {  // bf16 + bias (MoE h1)
                    Cb[o] = f2b(v + bias[col]);
                } else if (EPI == 5) {  // MoE out, first expert
                    Cf[o] = res[o] + coef[row] * (v + bias[col]);
                } else {                // MoE out, accumulate
                    Cf[o] += coef[row] * (v + bias[col]);
                }
            }
}

// ============================================================================
// Dual TN GEMM: p = swish(A@B1^T + bs; beta) * (A@B2^T + bg), bf16 out.
// A bf16 [M][K]; B1,B2 bf16 [N][K]. TILE 128x64 (x2 B). Depth-4 counted-vmcnt
// pipeline (K/32 multiple of 4 required; K=4096 at call site).
// ============================================================================
__global__ __launch_bounds__(256) void gemm_tn_dual(
    const u16* __restrict__ A, const u16* __restrict__ B1,
    const u16* __restrict__ B2, const float* __restrict__ bs,
    const float* __restrict__ bg, const float* __restrict__ betaP,
    u16* __restrict__ P, int K, int lda, int ldb, int ldc)
{
    constexpr int ABUF = 128 * 32;
    constexpr int BBUF = 64 * 32;
    constexpr int BUFSZ = ABUF + 2 * BBUF;   // 8192 u16 = 16KB
    constexpr int NPW = 4;
    __shared__ alignas(16) u16 L[4 * BUFSZ]; // 64 KB
    int tid = threadIdx.x;
    int bx = blockIdx.x, by = blockIdx.y;
    xcd_swizzle(bx, by);
    const u16* Ap  = A  + (size_t)by * 128 * lda;
    const u16* B1p = B1 + (size_t)bx * 64 * ldb;
    const u16* B2p = B2 + (size_t)bx * 64 * ldb;

    int lane = tid & 63, w = tid >> 6;
    int wr = (w >> 1) * 64, wc = (w & 1) * 32;
    int fm = lane & 15;

    // 16 instructions: 0-7 A, 8-11 B1, 12-15 B2 -> 4 per wave
    const u16* gsrc[4];
    int loff[4];
    #pragma unroll
    for (int ii = 0; ii < 4; ++ii) {
        int inst = w * 4 + ii;
        int lrow = lane >> 2;
        int sx = lane & 3;
        if (inst < 8) {
            int row = inst * 16 + lrow;
            gsrc[ii] = Ap + (size_t)row * lda + ((sx ^ ((row >> 1) & 3)) * 8);
            loff[ii] = inst * 512;
        } else if (inst < 12) {
            int row = (inst - 8) * 16 + lrow;
            gsrc[ii] = B1p + (size_t)row * ldb + ((sx ^ ((row >> 1) & 3)) * 8);
            loff[ii] = ABUF + (inst - 8) * 512;
        } else {
            int row = (inst - 12) * 16 + lrow;
            gsrc[ii] = B2p + (size_t)row * ldb + ((sx ^ ((row >> 1) & 3)) * 8);
            loff[ii] = ABUF + BBUF + (inst - 12) * 512;
        }
    }
    int aoff[4], boff[2];
    #pragma unroll
    for (int i = 0; i < 4; ++i) {
        int r = wr + i * 16 + fm;
        aoff[i] = r * 32 + (((lane >> 4) ^ ((r >> 1) & 3)) * 8);
    }
    #pragma unroll
    for (int j = 0; j < 2; ++j) {
        int r = wc + j * 16 + fm;
        boff[j] = ABUF + r * 32 + (((lane >> 4) ^ ((r >> 1) & 3)) * 8);
    }

    f32x4 a1[4][2], a2[4][2];
    #pragma unroll
    for (int i = 0; i < 4; ++i)
        #pragma unroll
        for (int j = 0; j < 2; ++j) {
            a1[i][j] = (f32x4){0.f, 0.f, 0.f, 0.f};
            a2[i][j] = (f32x4){0.f, 0.f, 0.f, 0.f};
        }

    auto STAGE = [&](int bufOff, int kk) {
        #pragma unroll
        for (int ii = 0; ii < 4; ++ii)
            gl_lds16(gsrc[ii] + kk, L + bufOff + loff[ii]);
    };
    auto COMPUTE = [&](int bufOff) {
        short8 af[4], b1f[2], b2f[2];
        #pragma unroll
        for (int i = 0; i < 4; ++i) af[i] = *(const short8*)(L + bufOff + aoff[i]);
        #pragma unroll
        for (int j = 0; j < 2; ++j) {
            b1f[j] = *(const short8*)(L + bufOff + boff[j]);
            b2f[j] = *(const short8*)(L + bufOff + BBUF + boff[j]);
        }
        __builtin_amdgcn_s_setprio(1);
        #pragma unroll
        for (int i = 0; i < 4; ++i)
            #pragma unroll
            for (int j = 0; j < 2; ++j) {
                a1[i][j] = __builtin_amdgcn_mfma_f32_16x16x32_bf16(af[i], b1f[j], a1[i][j], 0, 0, 0);
                a2[i][j] = __builtin_amdgcn_mfma_f32_16x16x32_bf16(af[i], b2f[j], a2[i][j], 0, 0, 0);
            }
        __builtin_amdgcn_s_setprio(0);
    };

    int nt = K >> 5;                      // 128
    STAGE(0 * BUFSZ, 0);
    STAGE(1 * BUFSZ, 32);
    STAGE(2 * BUFSZ, 64);
    auto PHASEF = [&](int bufC, int bufS, int kk) {
        STAGE(bufS, kk);
        waitvm<3 * NPW>();
        barrier_raw();
        COMPUTE(bufC);
        barrier_raw();
    };
    for (int p = 0; p < nt - 4; p += 4) {
        PHASEF(0 * BUFSZ, 3 * BUFSZ, (p + 3) * 32);
        PHASEF(1 * BUFSZ, 0 * BUFSZ, (p + 4) * 32);
        PHASEF(2 * BUFSZ, 1 * BUFSZ, (p + 5) * 32);
        PHASEF(3 * BUFSZ, 2 * BUFSZ, (p + 6) * 32);
    }
    STAGE(3 * BUFSZ, (nt - 1) * 32);
    waitvm<3 * NPW>(); barrier_raw(); COMPUTE(0 * BUFSZ); barrier_raw();
    waitvm<2 * NPW>(); barrier_raw(); COMPUTE(1 * BUFSZ); barrier_raw();
    waitvm<1 * NPW>(); barrier_raw(); COMPUTE(2 * BUFSZ); barrier_raw();
    waitvm<0>();       barrier_raw(); COMPUTE(3 * BUFSZ);

    float beta = betaP[0];
    int rBase = by * 128 + wr + (lane >> 4) * 4;
    int cBase = bx * 64 + wc + fm;
    #pragma unroll
    for (int i = 0; i < 4; ++i)
        #pragma unroll
        for (int j = 0; j < 2; ++j)
            #pragma unroll
            for (int r = 0; r < 4; ++r) {
                int row = rBase + i * 16 + r;
                int col = cBase + j * 16;
                float sx = a1[i][j][r] + bs[col];
                float gl = a2[i][j][r] + bg[col];
                float sw = sx / (1.f + expf(-beta * sx));
                P[(size_t)row * ldc + col] = f2b(sw * gl);
            }
}

// ============================================================================
// Weight transpose: f32 [K][N] -> bf16 [N][K], LDS-tiled 64x64.
// ============================================================================
__global__ __launch_bounds__(256) void transpose_w(
    const float* __restrict__ W, u16* __restrict__ out, int K, int N)
{
    __shared__ u16 Ls[64][66];
    int n0 = blockIdx.x * 64, k0 = blockIdx.y * 64;
    int tid = threadIdx.x;
    #pragma unroll
    for (int i = 0; i < 16; ++i) {
        int idx = tid + i * 256;
        int r = idx >> 6, c = idx & 63;           // r=k-local, c=n-local
        Ls[r][c] = f2b(W[(size_t)(k0 + r) * N + n0 + c]);
    }
    __syncthreads();
    #pragma unroll
    for (int i = 0; i < 16; ++i) {
        int idx = tid + i * 256;
        int n = idx >> 6, k = idx & 63;
        out[(size_t)(n0 + n) * K + k0 + k] = Ls[k][n];
    }
}

// ============================================================================
// Small kernels
// ============================================================================
// LayerNorm (ddof=1): out bf16 always; optional f32 copy.
__global__ __launch_bounds__(256) void ln_kernel(
    const float* __restrict__ x, const float* __restrict__ g,
    const float* __restrict__ b, u16* __restrict__ outB,
    float* __restrict__ outF, int wantF)
{
    int row = blockIdx.x;
    int tid = threadIdx.x;
    __shared__ float rs[256], rq[256];
    const float* xp = x + (size_t)row * C_;
    float s = 0.f, q = 0.f;
    for (int c = tid; c < C_; c += 256) {
        float v = xp[c];
        s += v; q += v * v;
    }
    rs[tid] = s; rq[tid] = q; __syncthreads();
    for (int off = 128; off > 0; off >>= 1) {
        if (tid < off) { rs[tid] += rs[tid + off]; rq[tid] += rq[tid + off]; }
        __syncthreads();
    }
    float mean = rs[0] * (1.f / C_);
    float var  = (rq[0] - (float)C_ * mean * mean) * (1.f / (C_ - 1));
    float inv  = rsqrtf(var + 1e-5f);
    for (int c = tid; c < C_; c += 256) {
        float v = (xp[c] - mean) * inv * g[c] + b[c];
        outB[(size_t)row * C_ + c] = f2b(v);
        if (wantF) outF[(size_t)row * C_ + c] = v;
    }
}

// Wk/Wv: f32 [H][C][D] -> bf16 [hd][c]
__global__ __launch_bounds__(256) void prep_whcd(const float* __restrict__ W, u16* __restrict__ out) {
    int idx = blockIdx.x * 256 + threadIdx.x;
    int hd = idx >> 10, c = idx & 1023;
    out[idx] = f2b(W[((size_t)(hd >> 6) * C_ + c) * 64 + (hd & 63)]);
}
// Wq summed over q: f32 [H][2][C][D] -> bf16 [hd][c]
__global__ __launch_bounds__(256) void prep_wq(const float* __restrict__ W, u16* __restrict__ out) {
    int idx = blockIdx.x * 256 + threadIdx.x;
    int hd = idx >> 10, c = idx & 1023;
    int h = hd >> 6, d = hd & 63;
    size_t i0 = (((size_t)h * 2 + 0) * C_ + c) * 64 + d;
    size_t i1 = (((size_t)h * 2 + 1) * C_ + c) * 64 + d;
    out[idx] = f2b(W[i0] + W[i1]);
}
// Wp: f32 [K][N] -> bf16 [N][K]
__global__ __launch_bounds__(256) void prep_wp(const float* __restrict__ W, u16* __restrict__ out) {
    int idx = blockIdx.x * 256 + threadIdx.x;
    int n = idx >> 10, k = idx & 1023;
    out[idx] = f2b(W[(size_t)k * C_ + n]);
}
// KrT[hb][s][d] = Kbf[(b*1024 + d*16 + (s>>6))*1024 + h*64 + (s&63)]
__global__ __launch_bounds__(256) void prep_krt(const u16* __restrict__ Kbf, u16* __restrict__ out) {
    int idx = blockIdx.x * 256 + threadIdx.x;
    int hb = idx >> 16, rem = idx & 65535;
    int s = rem >> 6, d = rem & 63;
    int h = hb >> 1, b = hb & 1;
    out[idx] = Kbf[((size_t)(b * 1024 + d * 16 + (s >> 6))) * 1024 + h * 64 + (s & 63)];
}
// VT[hb][d][s] = Vbf[(b*1024+s)*1024 + h*64 + d]
__global__ __launch_bounds__(256) void prep_vt(const u16* __restrict__ Vbf, u16* __restrict__ out) {
    int idx = blockIdx.x * 256 + threadIdx.x;
    int hb = idx >> 16, rem = idx & 65535;
    int d = rem >> 10, s = rem & 1023;
    int h = hb >> 1, b = hb & 1;
    out[idx] = Vbf[((size_t)(b * 1024 + s)) * 1024 + h * 64 + d];
}

// Row softmax over 1024 f32, in-place write as bf16 into row start.
__global__ __launch_bounds__(256) void softmax_rows(float* __restrict__ sc) {
    float* rp = sc + (size_t)blockIdx.x * 1024;
    int tid = threadIdx.x;
    float4 v = *(float4*)(rp + tid * 4);
    __shared__ float red[256];
    float mx = fmaxf(fmaxf(v.x, v.y), fmaxf(v.z, v.w));
    red[tid] = mx; __syncthreads();
    for (int off = 128; off > 0; off >>= 1) {
        if (tid < off) red[tid] = fmaxf(red[tid], red[tid + off]);
        __syncthreads();
    }
    mx = red[0]; __syncthreads();
    float e0 = expf(v.x - mx), e1 = expf(v.y - mx), e2 = expf(v.z - mx), e3 = expf(v.w - mx);
    red[tid] = e0 + e1 + e2 + e3; __syncthreads();
    for (int off = 128; off > 0; off >>= 1) {
        if (tid < off) red[tid] += red[tid + off];
        __syncthreads();
    }
    float inv = 1.f / red[0];
    u16* wp = (u16*)rp;
    wp[tid * 4 + 0] = f2b(e0 * inv);
    wp[tid * 4 + 1] = f2b(e1 * inv);
    wp[tid * 4 + 2] = f2b(e2 * inv);
    wp[tid * 4 + 3] = f2b(e3 * inv);
}

// Router: logits from f32 xn2, max + argmax per token.
__global__ __launch_bounds__(256) void router_kernel(
    const float* __restrict__ xn2, const float* __restrict__ Wg,
    const float* __restrict__ bgp, float* __restrict__ mOut, int* __restrict__ topiOut)
{
    int g = blockIdx.x;
    int tid = threadIdx.x;
    __shared__ float r0[256], r1[256];
    const float* xp = xn2 + (size_t)g * C_;
    float a0 = 0.f, a1 = 0.f;
    for (int c = tid; c < C_; c += 256) {
        float xv = xp[c];
        a0 += xv * Wg[c * 2 + 0];
        a1 += xv * Wg[c * 2 + 1];
    }
    r0[tid] = a0; r1[tid] = a1; __syncthreads();
    for (int off = 128; off > 0; off >>= 1) {
        if (tid < off) { r0[tid] += r0[tid + off]; r1[tid] += r1[tid + off]; }
        __syncthreads();
    }
    if (tid == 0) {
        float l0 = r0[0] + bgp[0];
        float l1 = r1[0] + bgp[1];
        topiOut[g] = (l1 > l0) ? 1 : 0;
        mOut[g] = fmaxf(l0, l1);
    }
}

// Softmax of max-logit over TOKEN axis (faithful bug) -> per-expert coef.
__global__ __launch_bounds__(256) void gatecoef_kernel(
    const float* __restrict__ m, const int* __restrict__ topi, float* __restrict__ coef)
{
    int b = blockIdx.x;
    int tid = threadIdx.x;
    __shared__ float red[256];
    const float* mp = m + (size_t)b * T_;
    float mx = -INFINITY;
    for (int t = tid; t < T_; t += 256) mx = fmaxf(mx, mp[t]);
    red[tid] = mx; __syncthreads();
    for (int off = 128; off > 0; off >>= 1) {
        if (tid < off) red[tid] = fmaxf(red[tid], red[tid + off]);
        __syncthreads();
    }
    mx = red[0]; __syncthreads();
    float s = 0.f;
    for (int t = tid; t < T_; t += 256) s += expf(mp[t] - mx);
    red[tid] = s; __syncthreads();
    for (int off = 128; off > 0; off >>= 1) {
        if (tid < off) red[tid] += red[tid + off];
        __syncthreads();
    }
    float inv = 1.f / red[0];
    for (int t = tid; t < T_; t += 256) {
        int g = b * T_ + t;
        float wv = expf(mp[t] - mx) * inv;
        int e = topi[g];
        coef[g]       = (e == 0) ? wv : 0.f;
        coef[BT_ + g] = (e == 1) ? wv : 0.f;
    }
}

// ============================================================================
// Host
// ============================================================================
extern "C" void kernel_launch(void* const* d_in, const int* in_sizes, int n_in,
                              void* d_out, int out_size, void* d_ws, size_t ws_size,
                              hipStream_t stream)
{
    const float* x    = (const float*)d_in[0];
    const float* Wq   = (const float*)d_in[1];
    const float* Wk   = (const float*)d_in[2];
    const float* Wv   = (const float*)d_in[3];
    const float* Wp   = (const float*)d_in[4];
    const float* bp   = (const float*)d_in[5];
    const float* ln1g = (const float*)d_in[6];
    const float* ln1b = (const float*)d_in[7];
    const float* ln2g = (const float*)d_in[8];
    const float* ln2b = (const float*)d_in[9];
    const float* Wg   = (const float*)d_in[10];
    const float* bg   = (const float*)d_in[11];
    const float* Ew1  = (const float*)d_in[12];
    const float* Eb1  = (const float*)d_in[13];
    const float* Ews  = (const float*)d_in[14];
    const float* Ebs  = (const float*)d_in[15];
    const float* Ebeta= (const float*)d_in[16];
    const float* Ewg  = (const float*)d_in[17];
    const float* Ebg  = (const float*)d_in[18];
    const float* Ew2  = (const float*)d_in[19];
    const float* Eb2  = (const float*)d_in[20];
    float* out = (float*)d_out;

    char* ws = (char*)d_ws;
    const size_t MB = 1024 * 1024;
    // Phase-A layout (offsets in bytes); phase-B aliases dead regions.
    u16*  xnbf   = (u16*) (ws + 0);        // 4 MB   (later: xn2bf)
    u16*  WqsT   = (u16*) (ws + 4*MB);     // 2 MB   (phase-B: W1T/W2T)
    u16*  WkT    = (u16*) (ws + 6*MB);     // 2 MB
    u16*  WvT    = (u16*) (ws + 8*MB);     // 2 MB
    u16*  WpT    = (u16*) (ws + 10*MB);    // 2 MB
    u16*  Qbf    = (u16*) (ws + 12*MB);    // 4 MB   (MoE: p 12-28)
    u16*  Kbf    = (u16*) (ws + 16*MB);    // 4 MB
    u16*  Vbf    = (u16*) (ws + 20*MB);    // 4 MB
    u16*  KrT    = (u16*) (ws + 24*MB);    // 4 MB
    u16*  VT     = (u16*) (ws + 28*MB);    // 4 MB   (later: xn2f 28-36)
    u16*  Obf    = (u16*) (ws + 32*MB);    // 4 MB
    float* x1    = (float*)(ws + 36*MB);   // 8 MB
    float* sc    = (float*)(ws + 44*MB);   // 32 MB scores chunk G=8 (MoE: h1 44-60)
    float* mbuf  = (float*)(ws + 61*MB);   // 8 KB  (written step 7, after sc dead)
    int*   topi  = (int*)  (ws + 61*MB + 16*1024);
    float* coef  = (float*)(ws + 61*MB + 32*1024);  // [2][2048]
    // Phase-B aliases
    u16*  xn2bf  = (u16*) (ws + 0);
    float* xn2f  = (float*)(ws + 28*MB);
    u16*  h1     = (u16*) (ws + 44*MB);    // 16 MB [2048][4096]
    u16*  pbuf   = (u16*) (ws + 12*MB);    // 16 MB [2048][4096]
    // Phase-B bf16 transposed expert weights
    u16*  W1T    = (u16*) (ws + 4*MB);     // 8 MB [4096][1024] (dead prep region)
    u16*  W2T    = (u16*) (ws + 4*MB);     // 8 MB [1024][4096] (sequenced after W1T)
    u16*  WsT    = (u16*) (ws + 62*MB);    // 32 MB [4096][4096]
    u16*  WgT    = (u16*) (ws + 94*MB);    // 32 MB [4096][4096]  -> peak ws = 126 MB

    // --- 1. LN1 -> bf16 ---
    ln_kernel<<<BT_, 256, 0, stream>>>(x, ln1g, ln1b, xnbf, nullptr, 0);

    // --- 2. weight prep ---
    prep_whcd<<<C_*C_/256, 256, 0, stream>>>(Wk, WkT);
    prep_whcd<<<C_*C_/256, 256, 0, stream>>>(Wv, WvT);
    prep_wq  <<<C_*C_/256, 256, 0, stream>>>(Wq, WqsT);
    prep_wp  <<<C_*C_/256, 256, 0, stream>>>(Wp, WpT);

    // --- 3. Q/K/V projections (TN, bf16 out) ---
    {
        dim3 grid(16, 16, 1);
        gemm_tn<2,1,0,1><<<grid, 256, 0, stream>>>(xnbf, WqsT, nullptr, Qbf, nullptr, nullptr, nullptr,
            C_, C_, C_, C_, 0, 0,0,0, 0,0, 0,0,0);
        gemm_tn<2,1,0,1><<<grid, 256, 0, stream>>>(xnbf, WkT, nullptr, Kbf, nullptr, nullptr, nullptr,
            C_, C_, C_, C_, 0, 0,0,0, 0,0, 0,0,0);
        gemm_tn<2,1,0,1><<<grid, 256, 0, stream>>>(xnbf, WvT, nullptr, Vbf, nullptr, nullptr, nullptr,
            C_, C_, C_, C_, 0, 0,0,0, 0,0, 0,0,0);
    }
    prep_krt<<<H_*B_*T_*64/256, 256, 0, stream>>>(Kbf, KrT);
    prep_vt <<<H_*B_*T_*64/256, 256, 0, stream>>>(Vbf, VT);

    // --- 4. attention in hb-chunks of G_ ---
    for (int chunk = 0; chunk < (H_*B_)/G_; ++chunk) {
        int hb0 = chunk * G_;
        // scores = Q·KrT^T * 0.125, window mask; f32 [G][1024][1024]  (K=64 -> simple path)
        gemm_tn<4,2,0,0><<<dim3(8, 8, G_), 256, 0, stream>>>(
            Qbf, KrT, sc, nullptr, nullptr, nullptr, nullptr,
            64, C_, 64, 1024, hb0,
            /*aCz*/0, /*aCb*/1048576, /*aCh*/64,
            /*bCb*/65536, /*bCh*/131072,
            /*cCz*/1048576, 0, 0);
        // softmax rows, in-place -> bf16
        softmax_rows<<<G_*1024, 256, 0, stream>>>(sc);
        // O = W·VT^T -> Obf[b*T+t][h*64+d]; WINK skips exact-zero K-prefix
        gemm_tn<2,1,1,1><<<dim3(1, 8, G_), 256, 0, stream>>>(
            (u16*)sc, VT, nullptr, Obf, nullptr, nullptr, nullptr,
            1024, 2048, 1024, 1024, hb0,
            /*aCz*/2097152, 0, 0,
            /*bCb*/65536, /*bCh*/131072,
            /*cCz*/0, /*cCb*/1048576, /*cCh*/64);
    }

    // --- 5. x1 = x + Obf@WpT + bp ---
    gemm_tn<2,3,0,1><<<dim3(16, 16, 1), 256, 0, stream>>>(
        Obf, WpT, x1, nullptr, bp, x, nullptr,
        C_, C_, C_, C_, 0, 0,0,0, 0,0, 0,0,0);

    // --- 6. LN2 (f32 for router + bf16 for GEMMs) ---
    ln_kernel<<<BT_, 256, 0, stream>>>(x1, ln2g, ln2b, xn2bf, xn2f, 1);

    // --- 7. router + gate ---
    router_kernel<<<BT_, 256, 0, stream>>>(xn2f, Wg, bg, mbuf, topi);
    gatecoef_kernel<<<B_, 256, 0, stream>>>(mbuf, topi, coef);

    // --- 8. MoE: pre-transposed bf16 weights, all GEMMs on TN deep path ---
    for (int e = 0; e < E_; ++e) {
        // W1T = Ew1[e]^T bf16 [4096][1024]
        transpose_w<<<dim3(NH_/64, C_/64), 256, 0, stream>>>(
            Ew1 + (size_t)e * C_ * NH_, W1T, C_, NH_);
        // h1 = xn2@Ew1[e] + Eb1[e] -> bf16 [2048][4096]
        gemm_tn<2,4,0,1><<<dim3(NH_/64, 16), 256, 0, stream>>>(
            xn2bf, W1T, nullptr, h1, Eb1 + (size_t)e * NH_, nullptr, nullptr,
            C_, C_, C_, NH_, 0, 0,0,0, 0,0, 0,0,0);
        // WsT/WgT = Ews[e]^T / Ewg[e]^T bf16 [4096][4096]
        transpose_w<<<dim3(NH_/64, NH_/64), 256, 0, stream>>>(
            Ews + (size_t)e * NH_ * NH_, WsT, NH_, NH_);
        transpose_w<<<dim3(NH_/64, NH_/64), 256, 0, stream>>>(
            Ewg + (size_t)e * NH_ * NH_, WgT, NH_, NH_);
        // p = swish(h1@Ews+Ebs) * (h1@Ewg+Ebg) -> bf16
        gemm_tn_dual<<<dim3(NH_/64, 16), 256, 0, stream>>>(
            h1, WsT, WgT, Ebs + (size_t)e * NH_, Ebg + (size_t)e * NH_, Ebeta + e,
            pbuf, NH_, NH_, NH_, NH_);
        // W2T = Ew2[e]^T bf16 [1024][4096]
        transpose_w<<<dim3(C_/64, NH_/64), 256, 0, stream>>>(
            Ew2 + (size_t)e * NH_ * C_, W2T, NH_, C_);
        // out (+)= coef_e * (p@Ew2[e] + Eb2[e])  (+ x1 on first pass)
        if (e == 0)
            gemm_tn<2,5,0,1><<<dim3(C_/64, 16), 256, 0, stream>>>(
                pbuf, W2T, out, nullptr, Eb2, x1, coef + 0 * BT_,
                NH_, NH_, NH_, C_, 0, 0,0,0, 0,0, 0,0,0);
        else
            gemm_tn<2,6,0,1><<<dim3(C_/64, 16), 256, 0, stream>>>(
                pbuf, W2T, out, nullptr, Eb2 + (size_t)e * C_, nullptr, coef + (size_t)e * BT_,
                NH_, NH_, NH_, C_, 0, 0,0,0, 0,0, 0,0,0);
    }
}

// Round 5
// 1014.488 us; speedup vs baseline: 1.6312x; 1.0270x over previous
//
#include <hip/hip_runtime.h>
#include <hip/hip_bf16.h>
#include <cmath>

#define B_    2
#define T_    1024
#define BT_   2048
#define C_    1024
#define H_    16
#define NH_   4096
#define E_    2
#define WIN_  256
#define G_    16         // attention hb-chunk size

typedef unsigned short u16;
typedef __attribute__((ext_vector_type(8))) short short8;
typedef __attribute__((ext_vector_type(4))) float f32x4;

__device__ __forceinline__ u16 f2b(float f) {
    __hip_bfloat16 h = __float2bfloat16(f);
    return *(u16*)&h;
}

// async global->LDS, 16B per lane; lds base must be wave-uniform (HW adds lane*16)
__device__ __forceinline__ void gl_lds16(const u16* g, u16* l) {
    __builtin_amdgcn_global_load_lds(
        (const __attribute__((address_space(1))) unsigned int*)g,
        (__attribute__((address_space(3))) unsigned int*)l, 16, 0, 0);
}

// counted vmcnt wait; "memory" clobber pins ordering vs loads/ds ops
template<int N> __device__ __forceinline__ void waitvm() {
    asm volatile("s_waitcnt vmcnt(%0)" :: "n"(N) : "memory");
}
// raw barrier fenced by sched_barrier so LDS reads/writes can't cross it
__device__ __forceinline__ void barrier_raw() {
    __builtin_amdgcn_sched_barrier(0);
    __builtin_amdgcn_s_barrier();
    __builtin_amdgcn_sched_barrier(0);
}

// XCD-chunked bijective swizzle (grids with x*y % 8 == 0): each XCD gets a
// contiguous logical-tile range -> B-panel slice stays in its L2.
__device__ __forceinline__ void xcd_swizzle(int& bx, int& by) {
    int gx = gridDim.x, gy = gridDim.y;
    int tot = gx * gy;
    if ((tot & 7) == 0) {
        int flat = by * gx + bx;
        int q = tot >> 3;
        int lg = (flat & 7) * q + (flat >> 3);
        bx = lg / gy; by = lg % gy;
    }
}

// ============================================================================
// MFMA GEMM, TN path: A bf16 [M][K] (lda), B bf16 [N][K] (ldb).
// TILE: 128 x (TNJ*32), BK=32. 4 waves 2x2. Batched via z with offset coefs.
// Staging: global_load_lds w16, linear LDS, XOR slot-swizzle on SOURCE+READ.
// PIPE=1: ring-3, stage-2-ahead, counted vmcnt (never 0 in loop), raw
//         barriers, register-rotated buffer offsets. Requires nt >= 3.
// PIPE=0: simple dbuf with __syncthreads (nt even).
// EPI: 0=f32, 1=bf16, 2=scores(scale+window-mask,f32), 3=x1(bias+res,f32),
//      4=bf16+bias, 5=f32 res+coef*(v+bias), 6=f32 +=coef*(v+bias)
// WINK: 1 = skip K-prefix below attention window (PV GEMM; exact-zero weights)
// ============================================================================
template<int TNJ, int EPI, int WINK, int PIPE>
__global__ __launch_bounds__(256) void gemm_tn(
    const u16* __restrict__ A, const u16* __restrict__ B,
    float* __restrict__ Cf, u16* __restrict__ Cb,
    const float* __restrict__ bias, const float* __restrict__ res,
    const float* __restrict__ coef,
    int K, int lda, int ldb, int ldc,
    int hb0, long aCz, long aCb, long aCh,
    long bCb, long bCh, long cCz, long cCb, long cCh)
{
    constexpr int TN = TNJ * 32;
    constexpr int ABUF = 128 * 32;       // u16 units
    constexpr int BBUF = TN * 32;
    constexpr int BUFSZ = ABUF + BBUF;
    constexpr int NDEEP = PIPE ? 3 : 2;
    constexpr int NINST = 8 + TN / 16;   // 1KB staging instructions per K-step
    constexpr int NPW = NINST / 4;       // per wave
    __shared__ alignas(16) u16 L[NDEEP * BUFSZ];
    int tid = threadIdx.x;
    int bx = blockIdx.x, by = blockIdx.y;
    xcd_swizzle(bx, by);
    int z = blockIdx.z;
    int hb = hb0 + z;
    int hh = hb >> 1, bb = hb & 1;
    const u16* Ap = A + aCz * z + aCb * bb + aCh * hh + (size_t)by * 128 * lda;
    const u16* Bp = B + bCb * bb + bCh * hh + (size_t)bx * TN * ldb;
    size_t cOff = (size_t)(cCz * z + cCb * bb + cCh * hh);

    int lane = tid & 63, w = tid >> 6;
    int wr = (w >> 1) * 64, wc = (w & 1) * (TNJ * 16);
    int fm = lane & 15;

    int rBase = by * 128 + wr + (lane >> 4) * 4;
    int cBase = bx * TN + wc + fm;

    // scores: fully-masked tile fast path (col <= row - WIN_ everywhere)
    if (EPI == 2) {
        if (bx * TN + TN - 1 <= by * 128 - WIN_) {
            #pragma unroll
            for (int i = 0; i < 4; ++i)
                #pragma unroll
                for (int j = 0; j < TNJ; ++j)
                    #pragma unroll
                    for (int r = 0; r < 4; ++r)
                        Cf[cOff + (size_t)(rBase + i * 16 + r) * ldc + cBase + j * 16] = -INFINITY;
            return;
        }
    }

    // PV: softmax weights are exactly 0 for col s <= row - WIN_; skip K-prefix.
    int kBeg = 0;
    if (WINK) {
        int s = by * 128 - (WIN_ - 1);
        kBeg = (s > 0) ? ((s >> 5) << 5) : 0;
    }

    // --- staging precompute: per-wave instructions, pre-swizzled global src ---
    const u16* gsrc[NPW];
    int loff[NPW];
    #pragma unroll
    for (int ii = 0; ii < NPW; ++ii) {
        int inst = w * NPW + ii;
        int lrow = lane >> 2;
        int sx = lane & 3;
        if (inst < 8) {
            int row = inst * 16 + lrow;
            gsrc[ii] = Ap + (size_t)row * lda + ((sx ^ ((row >> 1) & 3)) * 8);
            loff[ii] = inst * 512;
        } else {
            int row = (inst - 8) * 16 + lrow;
            gsrc[ii] = Bp + (size_t)row * ldb + ((sx ^ ((row >> 1) & 3)) * 8);
            loff[ii] = ABUF + (inst - 8) * 512;
        }
    }
    // --- fragment read offsets (u16 units), same XOR swizzle ---
    int aoff[4], boff[TNJ];
    #pragma unroll
    for (int i = 0; i < 4; ++i) {
        int r = wr + i * 16 + fm;
        aoff[i] = r * 32 + (((lane >> 4) ^ ((r >> 1) & 3)) * 8);
    }
    #pragma unroll
    for (int j = 0; j < TNJ; ++j) {
        int r = wc + j * 16 + fm;
        boff[j] = ABUF + r * 32 + (((lane >> 4) ^ ((r >> 1) & 3)) * 8);
    }

    f32x4 acc[4][TNJ];
    #pragma unroll
    for (int i = 0; i < 4; ++i)
        #pragma unroll
        for (int j = 0; j < TNJ; ++j)
            acc[i][j] = (f32x4){0.f, 0.f, 0.f, 0.f};

    auto STAGE = [&](int bufOff, int kk) {
        #pragma unroll
        for (int ii = 0; ii < NPW; ++ii)
            gl_lds16(gsrc[ii] + kk, L + bufOff + loff[ii]);
    };
    auto COMPUTE = [&](int bufOff) {
        short8 af[4], bf[TNJ];
        #pragma unroll
        for (int i = 0; i < 4; ++i) af[i] = *(const short8*)(L + bufOff + aoff[i]);
        #pragma unroll
        for (int j = 0; j < TNJ; ++j) bf[j] = *(const short8*)(L + bufOff + boff[j]);
        __builtin_amdgcn_s_setprio(1);
        #pragma unroll
        for (int i = 0; i < 4; ++i)
            #pragma unroll
            for (int j = 0; j < TNJ; ++j)
                acc[i][j] = __builtin_amdgcn_mfma_f32_16x16x32_bf16(af[i], bf[j], acc[i][j], 0, 0, 0);
        __builtin_amdgcn_s_setprio(0);
    };

    int nt = (K - kBeg) >> 5;

    if (PIPE) {
        // ring-3, stage-2-ahead; buffer offsets rotate through registers
        int b0 = 0, b1 = BUFSZ, b2 = 2 * BUFSZ;
        STAGE(b0, kBeg);
        STAGE(b1, kBeg + 32);
        for (int t = 0; t < nt - 2; ++t) {
            STAGE(b2, kBeg + (t + 2) * 32);
            waitvm<2 * NPW>();
            barrier_raw();
            COMPUTE(b0);
            barrier_raw();
            int tmp = b0; b0 = b1; b1 = b2; b2 = tmp;
        }
        waitvm<NPW>(); barrier_raw(); COMPUTE(b0);
        waitvm<0>();   barrier_raw(); COMPUTE(b1);
    } else {
        STAGE(0, kBeg);
        __syncthreads();
        for (int t = 0; t < nt; t += 2) {
            STAGE(BUFSZ, kBeg + (t + 1) * 32);
            COMPUTE(0);
            __syncthreads();
            if (t + 2 < nt) STAGE(0, kBeg + (t + 2) * 32);
            COMPUTE(BUFSZ);
            __syncthreads();
        }
    }

    #pragma unroll
    for (int i = 0; i < 4; ++i)
        #pragma unroll
        for (int j = 0; j < TNJ; ++j)
            #pragma unroll
            for (int r = 0; r < 4; ++r) {
                int row = rBase + i * 16 + r;
                int col = cBase + j * 16;
                float v = acc[i][j][r];
                size_t o = cOff + (size_t)row * ldc + col;
                if (EPI == 0) Cf[o] = v;
                else if (EPI == 1) Cb[o] = f2b(v);
                else if (EPI == 2) {
                    v *= 0.125f;
                    if (col <= row - WIN_) v = -INFINITY;  // past-window mask only
                    Cf[o] = v;
                } else if (EPI == 3) {  // X1: + bias + residual
                    Cf[o] = v + bias[col] + res[(size_t)row * ldc + col];
                } else if (EPI == 4) {  // bf16 + bias (MoE h1)
                    Cb[o] = f2b(v + bias[col]);
                } else if (EPI == 5) {  // MoE out, first expert
                    Cf[o] = res[o] + coef[row] * (v + bias[col]);
                } else {                // MoE out, accumulate
                    Cf[o] += coef[row] * (v + bias[col]);
                }
            }
}

// ============================================================================
// Dual TN GEMM: p = swish(A@B1^T + bs; beta) * (A@B2^T + bg), bf16 out.
// A bf16 [M][K]; B1,B2 bf16 [N][K]. TILE 128x64 (x2 B). Ring-3 counted-vmcnt
// pipeline (48 KB LDS -> 3 blocks/CU). nt >= 3 required (K=4096 -> 128).
// ============================================================================
__global__ __launch_bounds__(256) void gemm_tn_dual(
    const u16* __restrict__ A, const u16* __restrict__ B1,
    const u16* __restrict__ B2, const float* __restrict__ bs,
    const float* __restrict__ bg, const float* __restrict__ betaP,
    u16* __restrict__ P, int K, int lda, int ldb, int ldc)
{
    constexpr int ABUF = 128 * 32;
    constexpr int BBUF = 64 * 32;
    constexpr int BUFSZ = ABUF + 2 * BBUF;   // 8192 u16 = 16KB
    constexpr int NPW = 4;
    __shared__ alignas(16) u16 L[3 * BUFSZ]; // 48 KB
    int tid = threadIdx.x;
    int bx = blockIdx.x, by = blockIdx.y;
    xcd_swizzle(bx, by);
    const u16* Ap  = A  + (size_t)by * 128 * lda;
    const u16* B1p = B1 + (size_t)bx * 64 * ldb;
    const u16* B2p = B2 + (size_t)bx * 64 * ldb;

    int lane = tid & 63, w = tid >> 6;
    int wr = (w >> 1) * 64, wc = (w & 1) * 32;
    int fm = lane & 15;

    // 16 instructions: 0-7 A, 8-11 B1, 12-15 B2 -> 4 per wave
    const u16* gsrc[4];
    int loff[4];
    #pragma unroll
    for (int ii = 0; ii < 4; ++ii) {
        int inst = w * 4 + ii;
        int lrow = lane >> 2;
        int sx = lane & 3;
        if (inst < 8) {
            int row = inst * 16 + lrow;
            gsrc[ii] = Ap + (size_t)row * lda + ((sx ^ ((row >> 1) & 3)) * 8);
            loff[ii] = inst * 512;
        } else if (inst < 12) {
            int row = (inst - 8) * 16 + lrow;
            gsrc[ii] = B1p + (size_t)row * ldb + ((sx ^ ((row >> 1) & 3)) * 8);
            loff[ii] = ABUF + (inst - 8) * 512;
        } else {
            int row = (inst - 12) * 16 + lrow;
            gsrc[ii] = B2p + (size_t)row * ldb + ((sx ^ ((row >> 1) & 3)) * 8);
            loff[ii] = ABUF + BBUF + (inst - 12) * 512;
        }
    }
    int aoff[4], boff[2];
    #pragma unroll
    for (int i = 0; i < 4; ++i) {
        int r = wr + i * 16 + fm;
        aoff[i] = r * 32 + (((lane >> 4) ^ ((r >> 1) & 3)) * 8);
    }
    #pragma unroll
    for (int j = 0; j < 2; ++j) {
        int r = wc + j * 16 + fm;
        boff[j] = ABUF + r * 32 + (((lane >> 4) ^ ((r >> 1) & 3)) * 8);
    }

    f32x4 a1[4][2], a2[4][2];
    #pragma unroll
    for (int i = 0; i < 4; ++i)
        #pragma unroll
        for (int j = 0; j < 2; ++j) {
            a1[i][j] = (f32x4){0.f, 0.f, 0.f, 0.f};
            a2[i][j] = (f32x4){0.f, 0.f, 0.f, 0.f};
        }

    auto STAGE = [&](int bufOff, int kk) {
        #pragma unroll
        for (int ii = 0; ii < 4; ++ii)
            gl_lds16(gsrc[ii] + kk, L + bufOff + loff[ii]);
    };
    auto COMPUTE = [&](int bufOff) {
        short8 af[4], b1f[2], b2f[2];
        #pragma unroll
        for (int i = 0; i < 4; ++i) af[i] = *(const short8*)(L + bufOff + aoff[i]);
        #pragma unroll
        for (int j = 0; j < 2; ++j) {
            b1f[j] = *(const short8*)(L + bufOff + boff[j]);
            b2f[j] = *(const short8*)(L + bufOff + BBUF + boff[j]);
        }
        __builtin_amdgcn_s_setprio(1);
        #pragma unroll
        for (int i = 0; i < 4; ++i)
            #pragma unroll
            for (int j = 0; j < 2; ++j) {
                a1[i][j] = __builtin_amdgcn_mfma_f32_16x16x32_bf16(af[i], b1f[j], a1[i][j], 0, 0, 0);
                a2[i][j] = __builtin_amdgcn_mfma_f32_16x16x32_bf16(af[i], b2f[j], a2[i][j], 0, 0, 0);
            }
        __builtin_amdgcn_s_setprio(0);
    };

    int nt = K >> 5;                      // 128
    int b0 = 0, b1 = BUFSZ, b2 = 2 * BUFSZ;
    STAGE(b0, 0);
    STAGE(b1, 32);
    for (int t = 0; t < nt - 2; ++t) {
        STAGE(b2, (t + 2) * 32);
        waitvm<2 * NPW>();
        barrier_raw();
        COMPUTE(b0);
        barrier_raw();
        int tmp = b0; b0 = b1; b1 = b2; b2 = tmp;
    }
    waitvm<NPW>(); barrier_raw(); COMPUTE(b0);
    waitvm<0>();   barrier_raw(); COMPUTE(b1);

    float beta = betaP[0];
    int rBase = by * 128 + wr + (lane >> 4) * 4;
    int cBase = bx * 64 + wc + fm;
    #pragma unroll
    for (int i = 0; i < 4; ++i)
        #pragma unroll
        for (int j = 0; j < 2; ++j)
            #pragma unroll
            for (int r = 0; r < 4; ++r) {
                int row = rBase + i * 16 + r;
                int col = cBase + j * 16;
                float sx = a1[i][j][r] + bs[col];
                float gl = a2[i][j][r] + bg[col];
                float sw = sx / (1.f + expf(-beta * sx));
                P[(size_t)row * ldc + col] = f2b(sw * gl);
            }
}

// ============================================================================
// Weight transpose: f32 [K][N] -> bf16 [N][K], LDS-tiled 64x64.
// Vectorized: float4 reads (16B/lane), ushort4 writes (8B/lane).
// ============================================================================
__global__ __launch_bounds__(256) void transpose_w(
    const float* __restrict__ W, u16* __restrict__ out, int K, int N)
{
    __shared__ u16 Ls[64][68];     // row stride 136B: 8B-aligned, ~4-way write conflict
    int n0 = blockIdx.x * 64, k0 = blockIdx.y * 64;
    int tid = threadIdx.x;
    int r  = tid >> 4;             // 0..15
    int cg = (tid & 15) * 4;
    #pragma unroll
    for (int i = 0; i < 4; ++i) {
        int k = r + i * 16;
        float4 v = *(const float4*)&W[(size_t)(k0 + k) * N + n0 + cg];
        Ls[cg + 0][k] = f2b(v.x);
        Ls[cg + 1][k] = f2b(v.y);
        Ls[cg + 2][k] = f2b(v.z);
        Ls[cg + 3][k] = f2b(v.w);
    }
    __syncthreads();
    int n  = tid >> 4;
    int kg = (tid & 15) * 4;
    #pragma unroll
    for (int i = 0; i < 4; ++i) {
        int nn = n + i * 16;
        ushort4 v = *(const ushort4*)&Ls[nn][kg];
        *(ushort4*)&out[(size_t)(n0 + nn) * K + k0 + kg] = v;
    }
}

// ============================================================================
// Small kernels
// ============================================================================
// LayerNorm (ddof=1): out bf16 always; optional f32 copy.
__global__ __launch_bounds__(256) void ln_kernel(
    const float* __restrict__ x, const float* __restrict__ g,
    const float* __restrict__ b, u16* __restrict__ outB,
    float* __restrict__ outF, int wantF)
{
    int row = blockIdx.x;
    int tid = threadIdx.x;
    __shared__ float rs[256], rq[256];
    const float* xp = x + (size_t)row * C_;
    float s = 0.f, q = 0.f;
    for (int c = tid; c < C_; c += 256) {
        float v = xp[c];
        s += v; q += v * v;
    }
    rs[tid] = s; rq[tid] = q; __syncthreads();
    for (int off = 128; off > 0; off >>= 1) {
        if (tid < off) { rs[tid] += rs[tid + off]; rq[tid] += rq[tid + off]; }
        __syncthreads();
    }
    float mean = rs[0] * (1.f / C_);
    float var  = (rq[0] - (float)C_ * mean * mean) * (1.f / (C_ - 1));
    float inv  = rsqrtf(var + 1e-5f);
    for (int c = tid; c < C_; c += 256) {
        float v = (xp[c] - mean) * inv * g[c] + b[c];
        outB[(size_t)row * C_ + c] = f2b(v);
        if (wantF) outF[(size_t)row * C_ + c] = v;
    }
}

// Wk/Wv: f32 [H][C][D] -> bf16 [hd][c]
__global__ __launch_bounds__(256) void prep_whcd(const float* __restrict__ W, u16* __restrict__ out) {
    int idx = blockIdx.x * 256 + threadIdx.x;
    int hd = idx >> 10, c = idx & 1023;
    out[idx] = f2b(W[((size_t)(hd >> 6) * C_ + c) * 64 + (hd & 63)]);
}
// Wq summed over q: f32 [H][2][C][D] -> bf16 [hd][c]
__global__ __launch_bounds__(256) void prep_wq(const float* __restrict__ W, u16* __restrict__ out) {
    int idx = blockIdx.x * 256 + threadIdx.x;
    int hd = idx >> 10, c = idx & 1023;
    int h = hd >> 6, d = hd & 63;
    size_t i0 = (((size_t)h * 2 + 0) * C_ + c) * 64 + d;
    size_t i1 = (((size_t)h * 2 + 1) * C_ + c) * 64 + d;
    out[idx] = f2b(W[i0] + W[i1]);
}
// Wp: f32 [K][N] -> bf16 [N][K]
__global__ __launch_bounds__(256) void prep_wp(const float* __restrict__ W, u16* __restrict__ out) {
    int idx = blockIdx.x * 256 + threadIdx.x;
    int n = idx >> 10, k = idx & 1023;
    out[idx] = f2b(W[(size_t)k * C_ + n]);
}
// KrT[hb][s][d] = Kbf[(b*1024 + d*16 + (s>>6))*1024 + h*64 + (s&63)]
__global__ __launch_bounds__(256) void prep_krt(const u16* __restrict__ Kbf, u16* __restrict__ out) {
    int idx = blockIdx.x * 256 + threadIdx.x;
    int hb = idx >> 16, rem = idx & 65535;
    int s = rem >> 6, d = rem & 63;
    int h = hb >> 1, b = hb & 1;
    out[idx] = Kbf[((size_t)(b * 1024 + d * 16 + (s >> 6))) * 1024 + h * 64 + (s & 63)];
}
// VT[hb][d][s] = Vbf[(b*1024+s)*1024 + h*64 + d]
__global__ __launch_bounds__(256) void prep_vt(const u16* __restrict__ Vbf, u16* __restrict__ out) {
    int idx = blockIdx.x * 256 + threadIdx.x;
    int hb = idx >> 16, rem = idx & 65535;
    int d = rem >> 10, s = rem & 1023;
    int h = hb >> 1, b = hb & 1;
    out[idx] = Vbf[((size_t)(b * 1024 + s)) * 1024 + h * 64 + d];
}

// Row softmax over 1024 f32, in-place write as bf16 into row start.
__global__ __launch_bounds__(256) void softmax_rows(float* __restrict__ sc) {
    float* rp = sc + (size_t)blockIdx.x * 1024;
    int tid = threadIdx.x;
    float4 v = *(float4*)(rp + tid * 4);
    __shared__ float red[256];
    float mx = fmaxf(fmaxf(v.x, v.y), fmaxf(v.z, v.w));
    red[tid] = mx; __syncthreads();
    for (int off = 128; off > 0; off >>= 1) {
        if (tid < off) red[tid] = fmaxf(red[tid], red[tid + off]);
        __syncthreads();
    }
    mx = red[0]; __syncthreads();
    float e0 = expf(v.x - mx), e1 = expf(v.y - mx), e2 = expf(v.z - mx), e3 = expf(v.w - mx);
    red[tid] = e0 + e1 + e2 + e3; __syncthreads();
    for (int off = 128; off > 0; off >>= 1) {
        if (tid < off) red[tid] += red[tid + off];
        __syncthreads();
    }
    float inv = 1.f / red[0];
    u16* wp = (u16*)rp;
    wp[tid * 4 + 0] = f2b(e0 * inv);
    wp[tid * 4 + 1] = f2b(e1 * inv);
    wp[tid * 4 + 2] = f2b(e2 * inv);
    wp[tid * 4 + 3] = f2b(e3 * inv);
}

// Router: logits from f32 xn2, max + argmax per token.
__global__ __launch_bounds__(256) void router_kernel(
    const float* __restrict__ xn2, const float* __restrict__ Wg,
    const float* __restrict__ bgp, float* __restrict__ mOut, int* __restrict__ topiOut)
{
    int g = blockIdx.x;
    int tid = threadIdx.x;
    __shared__ float r0[256], r1[256];
    const float* xp = xn2 + (size_t)g * C_;
    float a0 = 0.f, a1 = 0.f;
    for (int c = tid; c < C_; c += 256) {
        float xv = xp[c];
        a0 += xv * Wg[c * 2 + 0];
        a1 += xv * Wg[c * 2 + 1];
    }
    r0[tid] = a0; r1[tid] = a1; __syncthreads();
    for (int off = 128; off > 0; off >>= 1) {
        if (tid < off) { r0[tid] += r0[tid + off]; r1[tid] += r1[tid + off]; }
        __syncthreads();
    }
    if (tid == 0) {
        float l0 = r0[0] + bgp[0];
        float l1 = r1[0] + bgp[1];
        topiOut[g] = (l1 > l0) ? 1 : 0;
        mOut[g] = fmaxf(l0, l1);
    }
}

// Softmax of max-logit over TOKEN axis (faithful bug) -> per-expert coef.
__global__ __launch_bounds__(256) void gatecoef_kernel(
    const float* __restrict__ m, const int* __restrict__ topi, float* __restrict__ coef)
{
    int b = blockIdx.x;
    int tid = threadIdx.x;
    __shared__ float red[256];
    const float* mp = m + (size_t)b * T_;
    float mx = -INFINITY;
    for (int t = tid; t < T_; t += 256) mx = fmaxf(mx, mp[t]);
    red[tid] = mx; __syncthreads();
    for (int off = 128; off > 0; off >>= 1) {
        if (tid < off) red[tid] = fmaxf(red[tid], red[tid + off]);
        __syncthreads();
    }
    mx = red[0]; __syncthreads();
    float s = 0.f;
    for (int t = tid; t < T_; t += 256) s += expf(mp[t] - mx);
    red[tid] = s; __syncthreads();
    for (int off = 128; off > 0; off >>= 1) {
        if (tid < off) red[tid] += red[tid + off];
        __syncthreads();
    }
    float inv = 1.f / red[0];
    for (int t = tid; t < T_; t += 256) {
        int g = b * T_ + t;
        float wv = expf(mp[t] - mx) * inv;
        int e = topi[g];
        coef[g]       = (e == 0) ? wv : 0.f;
        coef[BT_ + g] = (e == 1) ? wv : 0.f;
    }
}

// ============================================================================
// Host
// ============================================================================
extern "C" void kernel_launch(void* const* d_in, const int* in_sizes, int n_in,
                              void* d_out, int out_size, void* d_ws, size_t ws_size,
                              hipStream_t stream)
{
    const float* x    = (const float*)d_in[0];
    const float* Wq   = (const float*)d_in[1];
    const float* Wk   = (const float*)d_in[2];
    const float* Wv   = (const float*)d_in[3];
    const float* Wp   = (const float*)d_in[4];
    const float* bp   = (const float*)d_in[5];
    const float* ln1g = (const float*)d_in[6];
    const float* ln1b = (const float*)d_in[7];
    const float* ln2g = (const float*)d_in[8];
    const float* ln2b = (const float*)d_in[9];
    const float* Wg   = (const float*)d_in[10];
    const float* bg   = (const float*)d_in[11];
    const float* Ew1  = (const float*)d_in[12];
    const float* Eb1  = (const float*)d_in[13];
    const float* Ews  = (const float*)d_in[14];
    const float* Ebs  = (const float*)d_in[15];
    const float* Ebeta= (const float*)d_in[16];
    const float* Ewg  = (const float*)d_in[17];
    const float* Ebg  = (const float*)d_in[18];
    const float* Ew2  = (const float*)d_in[19];
    const float* Eb2  = (const float*)d_in[20];
    float* out = (float*)d_out;

    char* ws = (char*)d_ws;
    const size_t MB = 1024 * 1024;
    // Phase-A layout (offsets in bytes); phase-B aliases dead regions.
    u16*  xnbf   = (u16*) (ws + 0);        // 4 MB   (later: xn2bf)
    u16*  WqsT   = (u16*) (ws + 4*MB);     // 2 MB   (phase-B: W1T/W2T)
    u16*  WkT    = (u16*) (ws + 6*MB);     // 2 MB
    u16*  WvT    = (u16*) (ws + 8*MB);     // 2 MB
    u16*  WpT    = (u16*) (ws + 10*MB);    // 2 MB
    u16*  Qbf    = (u16*) (ws + 12*MB);    // 4 MB   (MoE: p 12-28)
    u16*  Kbf    = (u16*) (ws + 16*MB);    // 4 MB
    u16*  Vbf    = (u16*) (ws + 20*MB);    // 4 MB
    u16*  KrT    = (u16*) (ws + 24*MB);    // 4 MB
    u16*  VT     = (u16*) (ws + 28*MB);    // 4 MB   (later: xn2f 28-36)
    u16*  Obf    = (u16*) (ws + 32*MB);    // 4 MB
    float* x1    = (float*)(ws + 36*MB);   // 8 MB
    float* sc    = (float*)(ws + 44*MB);   // 64 MB scores chunk G=16 (MoE: h1 44-60, WsT 62-94, WgT 94-126 — all phase-B)
    // Phase-B aliases
    u16*  xn2bf  = (u16*) (ws + 0);
    float* xn2f  = (float*)(ws + 28*MB);
    u16*  h1     = (u16*) (ws + 44*MB);    // 16 MB [2048][4096]
    u16*  pbuf   = (u16*) (ws + 12*MB);    // 16 MB [2048][4096]
    u16*  W1T    = (u16*) (ws + 4*MB);     // 8 MB [4096][1024] (dead prep region)
    u16*  W2T    = (u16*) (ws + 4*MB);     // 8 MB [1024][4096] (sequenced after W1T)
    u16*  WsT    = (u16*) (ws + 62*MB);    // 32 MB [4096][4096]
    u16*  WgT    = (u16*) (ws + 94*MB);    // 32 MB [4096][4096]
    // Router scratch above WgT (written after sc dead; tiny)
    float* mbuf  = (float*)(ws + 126*MB);             // 8 KB
    int*   topi  = (int*)  (ws + 126*MB + 16*1024);
    float* coef  = (float*)(ws + 126*MB + 32*1024);   // [2][2048] -> peak ws ≈ 126.05 MB

    // --- 1. LN1 -> bf16 ---
    ln_kernel<<<BT_, 256, 0, stream>>>(x, ln1g, ln1b, xnbf, nullptr, 0);

    // --- 2. weight prep ---
    prep_whcd<<<C_*C_/256, 256, 0, stream>>>(Wk, WkT);
    prep_whcd<<<C_*C_/256, 256, 0, stream>>>(Wv, WvT);
    prep_wq  <<<C_*C_/256, 256, 0, stream>>>(Wq, WqsT);
    prep_wp  <<<C_*C_/256, 256, 0, stream>>>(Wp, WpT);

    // --- 3. Q/K/V projections (TN, bf16 out) ---
    {
        dim3 grid(16, 16, 1);
        gemm_tn<2,1,0,1><<<grid, 256, 0, stream>>>(xnbf, WqsT, nullptr, Qbf, nullptr, nullptr, nullptr,
            C_, C_, C_, C_, 0, 0,0,0, 0,0, 0,0,0);
        gemm_tn<2,1,0,1><<<grid, 256, 0, stream>>>(xnbf, WkT, nullptr, Kbf, nullptr, nullptr, nullptr,
            C_, C_, C_, C_, 0, 0,0,0, 0,0, 0,0,0);
        gemm_tn<2,1,0,1><<<grid, 256, 0, stream>>>(xnbf, WvT, nullptr, Vbf, nullptr, nullptr, nullptr,
            C_, C_, C_, C_, 0, 0,0,0, 0,0, 0,0,0);
    }
    prep_krt<<<H_*B_*T_*64/256, 256, 0, stream>>>(Kbf, KrT);
    prep_vt <<<H_*B_*T_*64/256, 256, 0, stream>>>(Vbf, VT);

    // --- 4. attention in hb-chunks of G_ ---
    for (int chunk = 0; chunk < (H_*B_)/G_; ++chunk) {
        int hb0 = chunk * G_;
        // scores = Q·KrT^T * 0.125, window mask; f32 [G][1024][1024]  (K=64 -> simple path)
        gemm_tn<4,2,0,0><<<dim3(8, 8, G_), 256, 0, stream>>>(
            Qbf, KrT, sc, nullptr, nullptr, nullptr, nullptr,
            64, C_, 64, 1024, hb0,
            /*aCz*/0, /*aCb*/1048576, /*aCh*/64,
            /*bCb*/65536, /*bCh*/131072,
            /*cCz*/1048576, 0, 0);
        // softmax rows, in-place -> bf16
        softmax_rows<<<G_*1024, 256, 0, stream>>>(sc);
        // O = W·VT^T -> Obf[b*T+t][h*64+d]; WINK skips exact-zero K-prefix
        gemm_tn<2,1,1,1><<<dim3(1, 8, G_), 256, 0, stream>>>(
            (u16*)sc, VT, nullptr, Obf, nullptr, nullptr, nullptr,
            1024, 2048, 1024, 1024, hb0,
            /*aCz*/2097152, 0, 0,
            /*bCb*/65536, /*bCh*/131072,
            /*cCz*/0, /*cCb*/1048576, /*cCh*/64);
    }

    // --- 5. x1 = x + Obf@WpT + bp ---
    gemm_tn<2,3,0,1><<<dim3(16, 16, 1), 256, 0, stream>>>(
        Obf, WpT, x1, nullptr, bp, x, nullptr,
        C_, C_, C_, C_, 0, 0,0,0, 0,0, 0,0,0);

    // --- 6. LN2 (f32 for router + bf16 for GEMMs) ---
    ln_kernel<<<BT_, 256, 0, stream>>>(x1, ln2g, ln2b, xn2bf, xn2f, 1);

    // --- 7. router + gate ---
    router_kernel<<<BT_, 256, 0, stream>>>(xn2f, Wg, bg, mbuf, topi);
    gatecoef_kernel<<<B_, 256, 0, stream>>>(mbuf, topi, coef);

    // --- 8. MoE: pre-transposed bf16 weights, all GEMMs on TN deep path ---
    for (int e = 0; e < E_; ++e) {
        // W1T = Ew1[e]^T bf16 [4096][1024]
        transpose_w<<<dim3(NH_/64, C_/64), 256, 0, stream>>>(
            Ew1 + (size_t)e * C_ * NH_, W1T, C_, NH_);
        // h1 = xn2@Ew1[e] + Eb1[e] -> bf16 [2048][4096]  (TNJ=4: better MFMA:LDS ratio)
        gemm_tn<4,4,0,1><<<dim3(NH_/128, 16), 256, 0, stream>>>(
            xn2bf, W1T, nullptr, h1, Eb1 + (size_t)e * NH_, nullptr, nullptr,
            C_, C_, C_, NH_, 0, 0,0,0, 0,0, 0,0,0);
        // WsT/WgT = Ews[e]^T / Ewg[e]^T bf16 [4096][4096]
        transpose_w<<<dim3(NH_/64, NH_/64), 256, 0, stream>>>(
            Ews + (size_t)e * NH_ * NH_, WsT, NH_, NH_);
        transpose_w<<<dim3(NH_/64, NH_/64), 256, 0, stream>>>(
            Ewg + (size_t)e * NH_ * NH_, WgT, NH_, NH_);
        // p = swish(h1@Ews+Ebs) * (h1@Ewg+Ebg) -> bf16
        gemm_tn_dual<<<dim3(NH_/64, 16), 256, 0, stream>>>(
            h1, WsT, WgT, Ebs + (size_t)e * NH_, Ebg + (size_t)e * NH_, Ebeta + e,
            pbuf, NH_, NH_, NH_, NH_);
        // W2T = Ew2[e]^T bf16 [1024][4096]
        transpose_w<<<dim3(C_/64, NH_/64), 256, 0, stream>>>(
            Ew2 + (size_t)e * NH_ * C_, W2T, NH_, C_);
        // out (+)= coef_e * (p@Ew2[e] + Eb2[e])  (+ x1 on first pass)
        if (e == 0)
            gemm_tn<2,5,0,1><<<dim3(C_/64, 16), 256, 0, stream>>>(
                pbuf, W2T, out, nullptr, Eb2, x1, coef + 0 * BT_,
                NH_, NH_, NH_, C_, 0, 0,0,0, 0,0, 0,0,0);
        else
            gemm_tn<2,6,0,1><<<dim3(C_/64, 16), 256, 0, stream>>>(
                pbuf, W2T, out, nullptr, Eb2 + (size_t)e * C_, nullptr, coef + (size_t)e * BT_,
                NH_, NH_, NH_, C_, 0, 0,0,0, 0,0, 0,0,0);
    }
}